// Round 10
// baseline (1767.556 us; speedup 1.0000x reference)
//
#include <hip/hip_runtime.h>

typedef _Float16 f16;
typedef _Float16 f16x8 __attribute__((ext_vector_type(8)));
typedef float f32x4 __attribute__((ext_vector_type(4)));
typedef float f32x16 __attribute__((ext_vector_type(16)));

// dims: b=16, C=512, t=8192, heads=16 (32 ch each)
// pipeline: gn_stats -> gn_apply(h f16, t-major) -> qk_w fused (w partials)
//           -> wreduce -> wpe(+bias') -> wfin = wpe@WvT -> out = x + bias' + Wfin@h

__device__ __forceinline__ void gl_lds16(const f16* g, const void* lds) {
    __builtin_amdgcn_global_load_lds((const __attribute__((address_space(1))) void*)g,
                                     (__attribute__((address_space(3))) void*)lds, 16, 0, 0);
}

// ---------------- K0: build Wqk_perm f16 [2 hg][512 rows][512] and WvT f16 [512 c][512 e] ----------------
// Wqkp row ri (within hg): hl=ri>>6 (head local 0..7), qk=(ri>>5)&1, ch=ri&31
__global__ __launch_bounds__(256) void k_convert(const float* __restrict__ wq, const float* __restrict__ wk,
                                                 const float* __restrict__ wv,
                                                 f16* __restrict__ Wqkp, f16* __restrict__ WvT) {
    int idx = blockIdx.x * 256 + threadIdx.x;
    if (idx < 524288) {
        int row = idx >> 9, c = idx & 511;
        int hg = row >> 9, ri = row & 511;
        int hl = ri >> 6, qk = (ri >> 5) & 1, ch = ri & 31;
        int src = (hg * 8 + hl) * 32 + ch;
        Wqkp[idx] = (f16)(qk ? wk[(size_t)src * 512 + c] : wq[(size_t)src * 512 + c]);
    } else if (idx < 786432) {
        int j = idx - 524288;
        int c = j >> 9, e = j & 511;
        WvT[j] = (f16)wv[(size_t)e * 512 + c];
    }
}

// ---------------- K1: groupnorm stats ----------------
__global__ __launch_bounds__(256) void k_gn_stats(const float* __restrict__ x, float* __restrict__ stats) {
    int tid = threadIdx.x;
    const float* base = x + (size_t)blockIdx.x * 16 * 8192;
    float s = 0.f, s2 = 0.f;
    for (int it = 0; it < 128; ++it) {
        f32x4 v = *(const f32x4*)(base + (size_t)(it * 256 + tid) * 4);
#pragma unroll
        for (int j = 0; j < 4; ++j) { s += v[j]; s2 += v[j] * v[j]; }
    }
    __shared__ float rs[256], rq[256];
    rs[tid] = s; rq[tid] = s2;
    __syncthreads();
    for (int off = 128; off > 0; off >>= 1) {
        if (tid < off) { rs[tid] += rs[tid + off]; rq[tid] += rq[tid + off]; }
        __syncthreads();
    }
    if (tid == 0) {
        float mean = rs[0] * (1.f / 131072.f);
        float var  = rq[0] * (1.f / 131072.f) - mean * mean;
        stats[blockIdx.x * 2 + 0] = mean;
        stats[blockIdx.x * 2 + 1] = rsqrtf(var + 1e-6f);
    }
}

// ---------------- K2: apply GN + transpose: x(b,c,t) f32 -> h(b,t,c) f16 ----------------
__global__ __launch_bounds__(256) void k_gn_apply(const float* __restrict__ x, const float* __restrict__ stats,
                                                  const float* __restrict__ gsc, const float* __restrict__ gbi,
                                                  f16* __restrict__ h) {
    __shared__ f16 ldsT[64][72];
    int tid = threadIdx.x;
    int tt = blockIdx.x & 127, ct = (blockIdx.x >> 7) & 7, b = blockIdx.x >> 10;
    int cc = tid >> 2, tq = tid & 3;
    int c = ct * 64 + cc;
    int g = c >> 4;
    float mean = stats[(b * 32 + g) * 2 + 0];
    float rstd = stats[(b * 32 + g) * 2 + 1];
    float sc = gsc[c] * rstd;
    float bi = gbi[c] - mean * sc;
    const float* xp = x + ((size_t)b * 512 + c) * 8192 + tt * 64 + tq * 16;
#pragma unroll
    for (int q4 = 0; q4 < 4; ++q4) {
        f32x4 v = *(const f32x4*)(xp + q4 * 4);
#pragma unroll
        for (int j = 0; j < 4; ++j) ldsT[tq * 16 + q4 * 4 + j][cc] = (f16)(v[j] * sc + bi);
    }
    __syncthreads();
    int tl = tid >> 2, cq = tid & 3;
    f16x8 v0 = *(const f16x8*)(&ldsT[tl][cq * 16]);
    f16x8 v1 = *(const f16x8*)(&ldsT[tl][cq * 16 + 8]);
    f16* hp = h + ((size_t)b * 8192 + tt * 64 + tl) * 512 + ct * 64 + cq * 16;
    *(f16x8*)(hp) = v0;
    *(f16x8*)(hp + 8) = v1;
}

// ---------------- shared GEMM core (BM=BN=128, BK=64, K=512) — used by k_wfin ----------------
__device__ __forceinline__ void gemm_core(const f16* __restrict__ Abase, int lda,
                                          const f16* __restrict__ Bbase,
                                          char* smem, int tid, f32x4 acc[4][4]) {
    const int lane = tid & 63, wave = tid >> 6;
    const int wm = wave >> 1, wn = wave & 1;
    char* As = smem;
    char* Bs = smem + 16384;
    const int srow = (lane >> 3);
    const int schunk = (lane & 7) ^ srow;
    for (int kt = 0; kt < 8; ++kt) {
#pragma unroll
        for (int i = 0; i < 4; ++i) {
            int row = (wave * 4 + i) * 8 + srow;
            gl_lds16(Abase + (size_t)row * lda + kt * 64 + schunk * 8, As + (wave * 4 + i) * 1024);
            gl_lds16(Bbase + (size_t)row * 512 + kt * 64 + schunk * 8, Bs + (wave * 4 + i) * 1024);
        }
        __syncthreads();
#pragma unroll
        for (int ks = 0; ks < 2; ++ks) {
            f16x8 af[4], bf[4];
#pragma unroll
            for (int i = 0; i < 4; ++i) {
                int row = wm * 64 + i * 16 + (lane & 15);
                int ch = (ks * 4 + (lane >> 4)) ^ (lane & 7);
                af[i] = *(const f16x8*)(As + row * 128 + ch * 16);
            }
#pragma unroll
            for (int j = 0; j < 4; ++j) {
                int row = wn * 64 + j * 16 + (lane & 15);
                int ch = (ks * 4 + (lane >> 4)) ^ (lane & 7);
                bf[j] = *(const f16x8*)(Bs + row * 128 + ch * 16);
            }
#pragma unroll
            for (int i = 0; i < 4; ++i)
#pragma unroll
                for (int j = 0; j < 4; ++j)
                    acc[i][j] = __builtin_amdgcn_mfma_f32_16x16x32_f16(af[i], bf[j], acc[i][j], 0, 0, 0);
        }
        __syncthreads();
    }
}

// ---------------- K3: fused qk GEMM + softmax + w partials — 8-wave BM=512 variant ----------------
// BM=512 (8 heads x {q32|k32}), BN=128 t, K=512. 512 thr / 8 waves; wave w owns head w (64 rows).
// LDS 80KB (A 64K + B 16K) -> 2 blk/CU = 16 waves/CU. Per-wave code identical to proven template.
__global__ __launch_bounds__(512, 4) void k_qk_w(const f16* __restrict__ h, const f16* __restrict__ Wqkp,
                                                 float* __restrict__ w_part) {
    __shared__ __align__(16) char smem[81920];
    int tid = threadIdx.x, lane = tid & 63, wave = tid >> 6;
    int bid = blockIdx.x;
    int lb = (bid & 7) * 256 + (bid >> 3);   // nwg=2048, bijective XCD swizzle
    int batch = lb >> 7;
    int rem = lb & 127;
    int tt = rem >> 1, hg = rem & 1;         // hg fastest: 2 blocks share one h tile
    const f16* Abase = Wqkp + (size_t)hg * 512 * 512;
    const f16* Bbase = h + ((size_t)batch * 8192 + (size_t)tt * 128) * 512;
    char* As = smem;            // 512 rows x 128 B = 65536
    char* Bs = smem + 65536;    // 128 rows x 128 B = 16384
    const int srow = lane >> 3;
    const int schunk = (lane & 7) ^ srow;
    f32x4 acc[4][8];
#pragma unroll
    for (int i = 0; i < 4; ++i)
#pragma unroll
        for (int j = 0; j < 8; ++j) acc[i][j] = (f32x4){0.f, 0.f, 0.f, 0.f};

    for (int kt = 0; kt < 8; ++kt) {
#pragma unroll
        for (int i = 0; i < 8; ++i) {
            int g = wave * 8 + i;
            gl_lds16(Abase + (size_t)(g * 8 + srow) * 512 + kt * 64 + schunk * 8, As + g * 1024);
        }
#pragma unroll
        for (int i = 0; i < 2; ++i) {
            int g = wave * 2 + i;
            gl_lds16(Bbase + (size_t)(g * 8 + srow) * 512 + kt * 64 + schunk * 8, Bs + g * 1024);
        }
        __syncthreads();
#pragma unroll
        for (int ks = 0; ks < 2; ++ks) {
            f16x8 af[4];
#pragma unroll
            for (int i = 0; i < 4; ++i) {
                int row = wave * 64 + i * 16 + (lane & 15);
                int ch = (ks * 4 + (lane >> 4)) ^ (lane & 7);
                af[i] = *(const f16x8*)(As + row * 128 + ch * 16);
            }
#pragma unroll
            for (int j = 0; j < 8; ++j) {
                int row = j * 16 + (lane & 15);
                int ch = (ks * 4 + (lane >> 4)) ^ (lane & 7);
                f16x8 bf = *(const f16x8*)(Bs + row * 128 + ch * 16);
#pragma unroll
                for (int i = 0; i < 4; ++i)
                    acc[i][j] = __builtin_amdgcn_mfma_f32_16x16x32_f16(af[i], bf, acc[i][j], 0, 0, 0);
            }
        }
        __syncthreads();
    }

    // ---- epilogue: per-wave (one head): softmax over 32 ch, w += q_sm @ k_sm^T ----
    f16* qbuf = (f16*)(smem + wave * 9216);   // 8 x 9216 = 73728 <= 81920
    f16* kbuf = qbuf + 32 * 72;
    f32x16 wacc;
#pragma unroll
    for (int i = 0; i < 16; ++i) wacc[i] = 0.f;

#pragma unroll
    for (int th = 0; th < 2; ++th) {
#pragma unroll
        for (int jl = 0; jl < 4; ++jl) {
            int j = th * 4 + jl;
#pragma unroll
            for (int qk = 0; qk < 2; ++qk) {
                int ib = qk * 2;
                float v0[8];
#pragma unroll
                for (int i2 = 0; i2 < 2; ++i2)
#pragma unroll
                    for (int r = 0; r < 4; ++r) v0[i2 * 4 + r] = acc[ib + i2][j][r];
                float mx = v0[0];
#pragma unroll
                for (int i = 1; i < 8; ++i) mx = fmaxf(mx, v0[i]);
                mx = fmaxf(mx, __shfl_xor(mx, 16));
                mx = fmaxf(mx, __shfl_xor(mx, 32));
                float s = 0.f;
#pragma unroll
                for (int i = 0; i < 8; ++i) { v0[i] = __expf(v0[i] - mx); s += v0[i]; }
                s += __shfl_xor(s, 16);
                s += __shfl_xor(s, 32);
                float inv = 1.f / s;
                f16* dst = qk ? kbuf : qbuf;
                int tcol = jl * 16 + (lane & 15);
#pragma unroll
                for (int i2 = 0; i2 < 2; ++i2)
#pragma unroll
                    for (int r = 0; r < 4; ++r) {
                        int c = i2 * 16 + (lane >> 4) * 4 + r;
                        dst[c * 72 + tcol] = (f16)(v0[i2 * 4 + r] * inv);
                    }
            }
        }
#pragma unroll
        for (int ks = 0; ks < 4; ++ks) {
            f16x8 a  = *(const f16x8*)(qbuf + (lane & 31) * 72 + ks * 16 + (lane >> 5) * 8);
            f16x8 bb = *(const f16x8*)(kbuf + (lane & 31) * 72 + ks * 16 + (lane >> 5) * 8);
            wacc = __builtin_amdgcn_mfma_f32_32x32x16_f16(a, bb, wacc, 0, 0, 0);
        }
    }
    int ghead = hg * 8 + wave;
    float* wpo = w_part + (((size_t)tt * 16 + batch) * 16 + ghead) * 1024;
#pragma unroll
    for (int r = 0; r < 16; ++r) {
        int row = (r & 3) + 8 * (r >> 2) + 4 * (lane >> 5);
        wpo[row * 32 + (lane & 31)] = wacc[r];
    }
}

// ---------------- K4: reduce w partials over 64 t-tiles ----------------
__global__ __launch_bounds__(256) void k_wreduce(const float* __restrict__ w_part, float* __restrict__ w_red) {
    int blk = blockIdx.x;   // b*16+head
    int tid = threadIdx.x;
    f32x4 s = (f32x4){0.f, 0.f, 0.f, 0.f};
    for (int tt = 0; tt < 64; ++tt) {
        f32x4 v = *(const f32x4*)(w_part + ((size_t)tt * 256 + blk) * 1024 + tid * 4);
        s += v;
    }
    *(f32x4*)(w_red + (size_t)blk * 1024 + tid * 4) = s;
}

// ---------------- K5: wpe[b][o][c] = sum_e wp[o][n32+e] w[b][n][e][c31]; bias'[b][o] ----------------
__global__ __launch_bounds__(256) void k_wpe(const float* __restrict__ w_red, const float* __restrict__ wp,
                                             const float* __restrict__ bv, const float* __restrict__ bp,
                                             f16* __restrict__ wpe, float* __restrict__ bias_p) {
    __shared__ float wl[16384];
    __shared__ float bred[256];
    int tid = threadIdx.x;
    int b = blockIdx.x >> 3, ot = blockIdx.x & 7;
    for (int idx = tid; idx < 16384; idx += 256) wl[idx] = w_red[(size_t)b * 16384 + idx];
    __syncthreads();
    int o = ot * 64 + (tid >> 2);
    int cq = tid & 3;
    float bacc = 0.f;
#pragma unroll
    for (int ng = 0; ng < 4; ++ng) {
        int n = cq * 4 + ng;
        float a[32];
#pragma unroll
        for (int d = 0; d < 32; ++d) a[d] = 0.f;
        for (int e = 0; e < 32; ++e) {
            float wv = wp[(size_t)o * 512 + n * 32 + e];
#pragma unroll
            for (int d = 0; d < 32; ++d) a[d] += wv * wl[n * 1024 + e * 32 + d];
        }
#pragma unroll
        for (int dc = 0; dc < 4; ++dc) {
            f16x8 o8;
#pragma unroll
            for (int j = 0; j < 8; ++j) o8[j] = (f16)a[dc * 8 + j];
            *(f16x8*)(wpe + ((size_t)b * 512 + o) * 512 + n * 32 + dc * 8) = o8;
        }
#pragma unroll
        for (int d = 0; d < 32; ++d) bacc += a[d] * bv[n * 32 + d];
    }
    bred[tid] = bacc;
    __syncthreads();
    if ((tid & 3) == 0)
        bias_p[(size_t)b * 512 + o] = bp[o] + bred[tid] + bred[tid + 1] + bred[tid + 2] + bred[tid + 3];
}

// ---------------- K6: Wfin[b] = wpe[b] @ WvT  (512x512x512 f16 GEMM per b) ----------------
__global__ __launch_bounds__(256) void k_wfin(const f16* __restrict__ wpe, const f16* __restrict__ WvT,
                                              f16* __restrict__ Wfin) {
    __shared__ __align__(16) char smem[34816];
    int tid = threadIdx.x, lane = tid & 63, wave = tid >> 6;
    int wm = wave >> 1, wn = wave & 1;
    int bid = blockIdx.x;
    int b = bid >> 4, mt = (bid >> 2) & 3, nt = bid & 3;
    const f16* Abase = wpe + (size_t)b * 262144 + (size_t)mt * 128 * 512;
    const f16* Bbase = WvT + (size_t)nt * 128 * 512;
    f32x4 acc[4][4];
#pragma unroll
    for (int i = 0; i < 4; ++i)
#pragma unroll
        for (int j = 0; j < 4; ++j) acc[i][j] = (f32x4){0.f, 0.f, 0.f, 0.f};
    gemm_core(Abase, 512, Bbase, smem, tid, acc);
    f16* epi = (f16*)smem;
#pragma unroll
    for (int i = 0; i < 4; ++i)
#pragma unroll
        for (int j = 0; j < 4; ++j)
#pragma unroll
            for (int r = 0; r < 4; ++r) {
                int m = wm * 64 + i * 16 + (lane >> 4) * 4 + r;
                int n = wn * 64 + j * 16 + (lane & 15);
                epi[m * 136 + n] = (f16)acc[i][j][r];
            }
    __syncthreads();
#pragma unroll
    for (int rr = 0; rr < 8; ++rr) {
        int row = wave * 32 + (lane >> 4) * 8 + rr;
        f16x8 vv = *(const f16x8*)(epi + row * 136 + (lane & 15) * 8);
        *(f16x8*)(Wfin + (size_t)b * 262144 + (size_t)(mt * 128 + row) * 512 + nt * 128 + (lane & 15) * 8) = vv;
    }
}

// ---------------- K7: out(b,c,t) f32 = x + bias' + Wfin[b] @ h — 8-wave BM=512 variant ----------------
// BM=512 (entire Wfin o-panel), BN=128 t. 512 thr / 8 waves, wave tile 64o x 128t, acc[4][8].
// LDS 80KB -> 2 blk/CU. h staged exactly once per (batch,tt). Epilogue: 4 passes x 2 waves through
// dual [64][132] f32 buffers (0-conflict) -> fully coalesced f32x4 x-load/out-store.
__global__ __launch_bounds__(512, 4) void k_out(const f16* __restrict__ h, const f16* __restrict__ Wfin,
                                                const float* __restrict__ x, const float* __restrict__ bias_p,
                                                float* __restrict__ out) {
    __shared__ __align__(16) char smem[81920];
    int tid = threadIdx.x, lane = tid & 63, wave = tid >> 6;
    int bid = blockIdx.x;
    int lb = (bid & 7) * 128 + (bid >> 3);   // nwg=1024, bijective XCD swizzle
    int batch = lb >> 6;
    int tt = lb & 63;
    const f16* Abase = Wfin + (size_t)batch * 262144;
    const f16* Bbase = h + ((size_t)batch * 8192 + (size_t)tt * 128) * 512;
    char* As = smem;            // 512 rows x 128 B = 65536
    char* Bs = smem + 65536;    // 128 rows x 128 B = 16384
    const int srow = lane >> 3;
    const int schunk = (lane & 7) ^ srow;
    f32x4 acc[4][8];
#pragma unroll
    for (int i = 0; i < 4; ++i)
#pragma unroll
        for (int j = 0; j < 8; ++j) acc[i][j] = (f32x4){0.f, 0.f, 0.f, 0.f};

    for (int kt = 0; kt < 8; ++kt) {
#pragma unroll
        for (int i = 0; i < 8; ++i) {
            int g = wave * 8 + i;
            gl_lds16(Abase + (size_t)(g * 8 + srow) * 512 + kt * 64 + schunk * 8, As + g * 1024);
        }
#pragma unroll
        for (int i = 0; i < 2; ++i) {
            int g = wave * 2 + i;
            gl_lds16(Bbase + (size_t)(g * 8 + srow) * 512 + kt * 64 + schunk * 8, Bs + g * 1024);
        }
        __syncthreads();
#pragma unroll
        for (int ks = 0; ks < 2; ++ks) {
            f16x8 af[4];
#pragma unroll
            for (int i = 0; i < 4; ++i) {
                int row = wave * 64 + i * 16 + (lane & 15);
                int ch = (ks * 4 + (lane >> 4)) ^ (lane & 7);
                af[i] = *(const f16x8*)(As + row * 128 + ch * 16);
            }
#pragma unroll
            for (int j = 0; j < 8; ++j) {
                int row = j * 16 + (lane & 15);
                int ch = (ks * 4 + (lane >> 4)) ^ (lane & 7);
                f16x8 bf = *(const f16x8*)(Bs + row * 128 + ch * 16);
#pragma unroll
                for (int i = 0; i < 4; ++i)
                    acc[i][j] = __builtin_amdgcn_mfma_f32_16x16x32_f16(af[i], bf, acc[i][j], 0, 0, 0);
            }
        }
        __syncthreads();
    }

    // acc[i][j][r]: o = wave*64 + i*16 + (lane>>4)*4 + r (0..511); t_l = j*16 + (lane&15) (0..127)
    float* ep0 = (float*)smem;               // [64][132] f32 = 33792 B
    float* ep1 = (float*)(smem + 33792);     // second buffer; 67584 <= 81920
    const int orow_in = (lane >> 4) * 4;
    for (int pp = 0; pp < 4; ++pp) {
        __syncthreads();                     // prev pass reads / gemm LDS done
        if ((wave >> 1) == pp) {
            float* ep = (wave & 1) ? ep1 : ep0;
#pragma unroll
            for (int i = 0; i < 4; ++i)
#pragma unroll
                for (int j = 0; j < 8; ++j)
#pragma unroll
                    for (int r = 0; r < 4; ++r)
                        ep[(i * 16 + orow_in + r) * 132 + j * 16 + (lane & 15)] = acc[i][j][r];
        }
        __syncthreads();
        int o_g0 = pp * 128;
#pragma unroll
        for (int p = 0; p < 8; ++p) {
            int idx = p * 512 + tid;         // 0..4095
            int row = idx >> 5;              // 0..127
            int tq = (idx & 31) * 4;         // 0..124
            const float* ep = (row < 64) ? ep0 : ep1;
            int r64 = row & 63;
            int o = o_g0 + row;
            float bpv = bias_p[batch * 512 + o];
            size_t g = ((size_t)batch * 512 + o) * 8192 + (size_t)tt * 128 + tq;
            f32x4 xv = *(const f32x4*)(x + g);
            f32x4 lv = *(const f32x4*)(ep + r64 * 132 + tq);
            f32x4 ov;
#pragma unroll
            for (int j = 0; j < 4; ++j) ov[j] = xv[j] + bpv + lv[j];
            *(f32x4*)(out + g) = ov;
        }
    }
}

extern "C" void kernel_launch(void* const* d_in, const int* in_sizes, int n_in,
                              void* d_out, int out_size, void* d_ws, size_t ws_size,
                              hipStream_t stream) {
    const float* x   = (const float*)d_in[0];
    const float* gsc = (const float*)d_in[1];
    const float* gbi = (const float*)d_in[2];
    const float* wq  = (const float*)d_in[3];
    const float* bq  = (const float*)d_in[4];  (void)bq;   // zero in setup (see R1 note)
    const float* wk  = (const float*)d_in[5];
    const float* bk  = (const float*)d_in[6];  (void)bk;   // zero in setup (see R1 note)
    const float* wv  = (const float*)d_in[7];
    const float* bv  = (const float*)d_in[8];
    const float* wp  = (const float*)d_in[9];
    const float* bp  = (const float*)d_in[10];
    float* out = (float*)d_out;
    char* ws = (char*)d_ws;

    size_t o_stats = 0;                        // 4 KB
    size_t o_wqkp  = 4096;                     // 1 MB
    size_t o_wvt   = o_wqkp + 1048576;         // 512 KB
    size_t o_biasp = o_wvt + 524288;           // 32 KB
    size_t o_wred  = o_biasp + 32768;          // 1 MB
    size_t o_wpe   = o_wred + 1048576;         // 8 MB
    size_t o_wfin  = o_wpe + 8388608;          // 8 MB
    size_t o_wpart = o_wfin + 8388608;         // 64 MB (64 tt x 16 b x 16 head x 1024)
    size_t o_h     = o_wpart + 67108864;       // 134 MB
    size_t total   = o_h + 134217728;          // ~223 MB
    if (ws_size < total) return;

    float* stats  = (float*)(ws + o_stats);
    f16*   Wqkp   = (f16*)(ws + o_wqkp);
    f16*   WvT    = (f16*)(ws + o_wvt);
    float* bias_p = (float*)(ws + o_biasp);
    float* w_red  = (float*)(ws + o_wred);
    f16*   wpe    = (f16*)(ws + o_wpe);
    f16*   Wfin   = (f16*)(ws + o_wfin);
    float* w_part = (float*)(ws + o_wpart);
    f16*   h      = (f16*)(ws + o_h);

    k_convert <<<3072,  256, 0, stream>>>(wq, wk, wv, Wqkp, WvT);
    k_gn_stats<<<512,   256, 0, stream>>>(x, stats);
    k_gn_apply<<<16384, 256, 0, stream>>>(x, stats, gsc, gbi, h);
    k_qk_w    <<<2048,  512, 0, stream>>>(h, Wqkp, w_part);
    k_wreduce <<<256,   256, 0, stream>>>(w_part, w_red);
    k_wpe     <<<128,   256, 0, stream>>>(w_red, wp, bv, bp, wpe, bias_p);
    k_wfin    <<<256,   256, 0, stream>>>(wpe, WvT, Wfin);
    k_out     <<<1024,  512, 0, stream>>>(h, Wfin, x, bias_p, out);
}

// Round 11
// 530.762 us; speedup vs baseline: 3.3302x; 3.3302x over previous
//
#include <hip/hip_runtime.h>

typedef _Float16 f16;
typedef _Float16 f16x8 __attribute__((ext_vector_type(8)));
typedef float f32x4 __attribute__((ext_vector_type(4)));
typedef float f32x16 __attribute__((ext_vector_type(16)));

// dims: b=16, C=512, t=8192, heads=16 (32 ch each)
// pipeline: [gn_stats+convert fused] -> gn_apply(h f16, t-major) -> qk_w fused (w partials)
//           -> wreduce -> wpe(+bias') -> wfin = wpe@WvT -> out = x + bias' + Wfin@h

__device__ __forceinline__ void gl_lds16(const f16* g, const void* lds) {
    __builtin_amdgcn_global_load_lds((const __attribute__((address_space(1))) void*)g,
                                     (__attribute__((address_space(3))) void*)lds, 16, 0, 0);
}

// ---------------- K1: fused groupnorm stats (blocks 0..511) + weight convert (blocks 512..3583) ----------------
// Wqkp f16 [4 hg][256 rows][512], row ri: hl=ri>>6, qk=(ri>>5)&1, ch=ri&31 -> src (hg*4+hl)*32+ch
// WvT f16 [512 c][512 e]
__global__ __launch_bounds__(256) void k_stats_conv(const float* __restrict__ x, float* __restrict__ stats,
                                                    const float* __restrict__ wq, const float* __restrict__ wk,
                                                    const float* __restrict__ wv,
                                                    f16* __restrict__ Wqkp, f16* __restrict__ WvT) {
    int tid = threadIdx.x;
    if (blockIdx.x >= 512) {
        int idx = (blockIdx.x - 512) * 256 + tid;
        if (idx < 524288) {
            int row = idx >> 9, c = idx & 511;
            int hg = row >> 8, ri = row & 255;
            int hl = ri >> 6, qk = (ri >> 5) & 1, ch = ri & 31;
            int src = (hg * 4 + hl) * 32 + ch;
            Wqkp[idx] = (f16)(qk ? wk[(size_t)src * 512 + c] : wq[(size_t)src * 512 + c]);
        } else if (idx < 786432) {
            int j = idx - 524288;
            int c = j >> 9, e = j & 511;
            WvT[j] = (f16)wv[(size_t)e * 512 + c];
        }
        return;
    }
    const float* base = x + (size_t)blockIdx.x * 16 * 8192;
    float s = 0.f, s2 = 0.f;
    for (int it = 0; it < 128; ++it) {
        f32x4 v = *(const f32x4*)(base + (size_t)(it * 256 + tid) * 4);
#pragma unroll
        for (int j = 0; j < 4; ++j) { s += v[j]; s2 += v[j] * v[j]; }
    }
    __shared__ float rs[256], rq[256];
    rs[tid] = s; rq[tid] = s2;
    __syncthreads();
    for (int off = 128; off > 0; off >>= 1) {
        if (tid < off) { rs[tid] += rs[tid + off]; rq[tid] += rq[tid + off]; }
        __syncthreads();
    }
    if (tid == 0) {
        float mean = rs[0] * (1.f / 131072.f);
        float var  = rq[0] * (1.f / 131072.f) - mean * mean;
        stats[blockIdx.x * 2 + 0] = mean;
        stats[blockIdx.x * 2 + 1] = rsqrtf(var + 1e-6f);
    }
}

// ---------------- K2: apply GN + transpose: x(b,c,t) f32 -> h(b,t,c) f16 ----------------
__global__ __launch_bounds__(256) void k_gn_apply(const float* __restrict__ x, const float* __restrict__ stats,
                                                  const float* __restrict__ gsc, const float* __restrict__ gbi,
                                                  f16* __restrict__ h) {
    __shared__ f16 ldsT[64][72];
    int tid = threadIdx.x;
    int tt = blockIdx.x & 127, ct = (blockIdx.x >> 7) & 7, b = blockIdx.x >> 10;
    int cc = tid >> 2, tq = tid & 3;
    int c = ct * 64 + cc;
    int g = c >> 4;
    float mean = stats[(b * 32 + g) * 2 + 0];
    float rstd = stats[(b * 32 + g) * 2 + 1];
    float sc = gsc[c] * rstd;
    float bi = gbi[c] - mean * sc;
    const float* xp = x + ((size_t)b * 512 + c) * 8192 + tt * 64 + tq * 16;
#pragma unroll
    for (int q4 = 0; q4 < 4; ++q4) {
        f32x4 v = *(const f32x4*)(xp + q4 * 4);
#pragma unroll
        for (int j = 0; j < 4; ++j) ldsT[tq * 16 + q4 * 4 + j][cc] = (f16)(v[j] * sc + bi);
    }
    __syncthreads();
    int tl = tid >> 2, cq = tid & 3;
    f16x8 v0 = *(const f16x8*)(&ldsT[tl][cq * 16]);
    f16x8 v1 = *(const f16x8*)(&ldsT[tl][cq * 16 + 8]);
    f16* hp = h + ((size_t)b * 8192 + tt * 64 + tl) * 512 + ct * 64 + cq * 16;
    *(f16x8*)(hp) = v0;
    *(f16x8*)(hp + 8) = v1;
}

// ---------------- shared GEMM core (BM=BN=128, BK=64, K=512) — used by k_wfin ----------------
__device__ __forceinline__ void gemm_core(const f16* __restrict__ Abase, int lda,
                                          const f16* __restrict__ Bbase,
                                          char* smem, int tid, f32x4 acc[4][4]) {
    const int lane = tid & 63, wave = tid >> 6;
    const int wm = wave >> 1, wn = wave & 1;
    char* As = smem;
    char* Bs = smem + 16384;
    const int srow = (lane >> 3);
    const int schunk = (lane & 7) ^ srow;
    for (int kt = 0; kt < 8; ++kt) {
#pragma unroll
        for (int i = 0; i < 4; ++i) {
            int row = (wave * 4 + i) * 8 + srow;
            gl_lds16(Abase + (size_t)row * lda + kt * 64 + schunk * 8, As + (wave * 4 + i) * 1024);
            gl_lds16(Bbase + (size_t)row * 512 + kt * 64 + schunk * 8, Bs + (wave * 4 + i) * 1024);
        }
        __syncthreads();
#pragma unroll
        for (int ks = 0; ks < 2; ++ks) {
            f16x8 af[4], bf[4];
#pragma unroll
            for (int i = 0; i < 4; ++i) {
                int row = wm * 64 + i * 16 + (lane & 15);
                int ch = (ks * 4 + (lane >> 4)) ^ (lane & 7);
                af[i] = *(const f16x8*)(As + row * 128 + ch * 16);
            }
#pragma unroll
            for (int j = 0; j < 4; ++j) {
                int row = wn * 64 + j * 16 + (lane & 15);
                int ch = (ks * 4 + (lane >> 4)) ^ (lane & 7);
                bf[j] = *(const f16x8*)(Bs + row * 128 + ch * 16);
            }
#pragma unroll
            for (int i = 0; i < 4; ++i)
#pragma unroll
                for (int j = 0; j < 4; ++j)
                    acc[i][j] = __builtin_amdgcn_mfma_f32_16x16x32_f16(af[i], bf[j], acc[i][j], 0, 0, 0);
        }
        __syncthreads();
    }
}

// ---------------- K3: fused qk GEMM + softmax + w partials (proven 2-barrier version) ----------------
// BM=256 (4 heads x {q32|k32}), BN=128 t, K=512. wave w owns head w of the group. 48KB LDS -> 3 blk/CU.
__global__ __launch_bounds__(256, 2) void k_qk_w(const f16* __restrict__ h, const f16* __restrict__ Wqkp,
                                                 float* __restrict__ w_part) {
    __shared__ __align__(16) char smem[49152];
    int tid = threadIdx.x, lane = tid & 63, wave = tid >> 6;
    int bid = blockIdx.x;
    int lb = (bid & 7) * 512 + (bid >> 3);   // nwg=4096, bijective XCD swizzle
    int batch = lb >> 8;
    int rem = lb & 255;
    int tt = rem >> 2, hg = rem & 3;         // hg fastest: 4 blocks share one h tile
    const f16* Abase = Wqkp + (size_t)hg * 256 * 512;
    const f16* Bbase = h + ((size_t)batch * 8192 + (size_t)tt * 128) * 512;
    char* As = smem;            // 256 rows x 128 B = 32768
    char* Bs = smem + 32768;    // 128 rows x 128 B = 16384
    const int srow = lane >> 3;
    const int schunk = (lane & 7) ^ srow;
    f32x4 acc[4][8];
#pragma unroll
    for (int i = 0; i < 4; ++i)
#pragma unroll
        for (int j = 0; j < 8; ++j) acc[i][j] = (f32x4){0.f, 0.f, 0.f, 0.f};

    for (int kt = 0; kt < 8; ++kt) {
#pragma unroll
        for (int i = 0; i < 8; ++i) {
            int g = wave * 8 + i;
            gl_lds16(Abase + (size_t)(g * 8 + srow) * 512 + kt * 64 + schunk * 8, As + g * 1024);
        }
#pragma unroll
        for (int i = 0; i < 4; ++i) {
            int g = wave * 4 + i;
            gl_lds16(Bbase + (size_t)(g * 8 + srow) * 512 + kt * 64 + schunk * 8, Bs + g * 1024);
        }
        __syncthreads();
#pragma unroll
        for (int ks = 0; ks < 2; ++ks) {
            f16x8 af[4];
#pragma unroll
            for (int i = 0; i < 4; ++i) {
                int row = wave * 64 + i * 16 + (lane & 15);
                int ch = (ks * 4 + (lane >> 4)) ^ (lane & 7);
                af[i] = *(const f16x8*)(As + row * 128 + ch * 16);
            }
#pragma unroll
            for (int j = 0; j < 8; ++j) {
                int row = j * 16 + (lane & 15);
                int ch = (ks * 4 + (lane >> 4)) ^ (lane & 7);
                f16x8 bf = *(const f16x8*)(Bs + row * 128 + ch * 16);
#pragma unroll
                for (int i = 0; i < 4; ++i)
                    acc[i][j] = __builtin_amdgcn_mfma_f32_16x16x32_f16(af[i], bf, acc[i][j], 0, 0, 0);
            }
        }
        __syncthreads();
    }

    // ---- epilogue: per-wave (one head): softmax over 32 ch, w += q_sm @ k_sm^T ----
    f16* qbuf = (f16*)(smem + wave * 9216);
    f16* kbuf = qbuf + 32 * 72;
    f32x16 wacc;
#pragma unroll
    for (int i = 0; i < 16; ++i) wacc[i] = 0.f;

#pragma unroll
    for (int th = 0; th < 2; ++th) {
#pragma unroll
        for (int jl = 0; jl < 4; ++jl) {
            int j = th * 4 + jl;
#pragma unroll
            for (int qk = 0; qk < 2; ++qk) {
                int ib = qk * 2;
                float v0[8];
#pragma unroll
                for (int i2 = 0; i2 < 2; ++i2)
#pragma unroll
                    for (int r = 0; r < 4; ++r) v0[i2 * 4 + r] = acc[ib + i2][j][r];
                float mx = v0[0];
#pragma unroll
                for (int i = 1; i < 8; ++i) mx = fmaxf(mx, v0[i]);
                mx = fmaxf(mx, __shfl_xor(mx, 16));
                mx = fmaxf(mx, __shfl_xor(mx, 32));
                float s = 0.f;
#pragma unroll
                for (int i = 0; i < 8; ++i) { v0[i] = __expf(v0[i] - mx); s += v0[i]; }
                s += __shfl_xor(s, 16);
                s += __shfl_xor(s, 32);
                float inv = 1.f / s;
                f16* dst = qk ? kbuf : qbuf;
                int tcol = jl * 16 + (lane & 15);
#pragma unroll
                for (int i2 = 0; i2 < 2; ++i2)
#pragma unroll
                    for (int r = 0; r < 4; ++r) {
                        int c = i2 * 16 + (lane >> 4) * 4 + r;
                        dst[c * 72 + tcol] = (f16)(v0[i2 * 4 + r] * inv);
                    }
            }
        }
#pragma unroll
        for (int ks = 0; ks < 4; ++ks) {
            f16x8 a  = *(const f16x8*)(qbuf + (lane & 31) * 72 + ks * 16 + (lane >> 5) * 8);
            f16x8 bb = *(const f16x8*)(kbuf + (lane & 31) * 72 + ks * 16 + (lane >> 5) * 8);
            wacc = __builtin_amdgcn_mfma_f32_32x32x16_f16(a, bb, wacc, 0, 0, 0);
        }
    }
    int ghead = hg * 4 + wave;
    float* wpo = w_part + (((size_t)tt * 16 + batch) * 16 + ghead) * 1024;
#pragma unroll
    for (int r = 0; r < 16; ++r) {
        int row = (r & 3) + 8 * (r >> 2) + 4 * (lane >> 5);
        wpo[row * 32 + (lane & 31)] = wacc[r];
    }
}

// ---------------- K4: reduce w partials over 64 t-tiles ----------------
__global__ __launch_bounds__(256) void k_wreduce(const float* __restrict__ w_part, float* __restrict__ w_red) {
    int blk = blockIdx.x;   // b*16+head
    int tid = threadIdx.x;
    f32x4 s = (f32x4){0.f, 0.f, 0.f, 0.f};
    for (int tt = 0; tt < 64; ++tt) {
        f32x4 v = *(const f32x4*)(w_part + ((size_t)tt * 256 + blk) * 1024 + tid * 4);
        s += v;
    }
    *(f32x4*)(w_red + (size_t)blk * 1024 + tid * 4) = s;
}

// ---------------- K5: wpe[b][o][c] = sum_e wp[o][n32+e] w[b][n][e][c31]; bias'[b][o] ----------------
__global__ __launch_bounds__(256) void k_wpe(const float* __restrict__ w_red, const float* __restrict__ wp,
                                             const float* __restrict__ bv, const float* __restrict__ bp,
                                             f16* __restrict__ wpe, float* __restrict__ bias_p) {
    __shared__ float wl[16384];
    __shared__ float bred[256];
    int tid = threadIdx.x;
    int b = blockIdx.x >> 3, ot = blockIdx.x & 7;
    for (int idx = tid; idx < 16384; idx += 256) wl[idx] = w_red[(size_t)b * 16384 + idx];
    __syncthreads();
    int o = ot * 64 + (tid >> 2);
    int cq = tid & 3;
    float bacc = 0.f;
#pragma unroll
    for (int ng = 0; ng < 4; ++ng) {
        int n = cq * 4 + ng;
        float a[32];
#pragma unroll
        for (int d = 0; d < 32; ++d) a[d] = 0.f;
        for (int e = 0; e < 32; ++e) {
            float wv = wp[(size_t)o * 512 + n * 32 + e];
#pragma unroll
            for (int d = 0; d < 32; ++d) a[d] += wv * wl[n * 1024 + e * 32 + d];
        }
#pragma unroll
        for (int dc = 0; dc < 4; ++dc) {
            f16x8 o8;
#pragma unroll
            for (int j = 0; j < 8; ++j) o8[j] = (f16)a[dc * 8 + j];
            *(f16x8*)(wpe + ((size_t)b * 512 + o) * 512 + n * 32 + dc * 8) = o8;
        }
#pragma unroll
        for (int d = 0; d < 32; ++d) bacc += a[d] * bv[n * 32 + d];
    }
    bred[tid] = bacc;
    __syncthreads();
    if ((tid & 3) == 0)
        bias_p[(size_t)b * 512 + o] = bp[o] + bred[tid] + bred[tid + 1] + bred[tid + 2] + bred[tid + 3];
}

// ---------------- K6: Wfin[b] = wpe[b] @ WvT  (512x512x512 f16 GEMM per b) ----------------
__global__ __launch_bounds__(256) void k_wfin(const f16* __restrict__ wpe, const f16* __restrict__ WvT,
                                              f16* __restrict__ Wfin) {
    __shared__ __align__(16) char smem[34816];
    int tid = threadIdx.x, lane = tid & 63, wave = tid >> 6;
    int wm = wave >> 1, wn = wave & 1;
    int bid = blockIdx.x;
    int b = bid >> 4, mt = (bid >> 2) & 3, nt = bid & 3;
    const f16* Abase = wpe + (size_t)b * 262144 + (size_t)mt * 128 * 512;
    const f16* Bbase = WvT + (size_t)nt * 128 * 512;
    f32x4 acc[4][4];
#pragma unroll
    for (int i = 0; i < 4; ++i)
#pragma unroll
        for (int j = 0; j < 4; ++j) acc[i][j] = (f32x4){0.f, 0.f, 0.f, 0.f};
    gemm_core(Abase, 512, Bbase, smem, tid, acc);
    f16* epi = (f16*)smem;
#pragma unroll
    for (int i = 0; i < 4; ++i)
#pragma unroll
        for (int j = 0; j < 4; ++j)
#pragma unroll
            for (int r = 0; r < 4; ++r) {
                int m = wm * 64 + i * 16 + (lane >> 4) * 4 + r;
                int n = wn * 64 + j * 16 + (lane & 15);
                epi[m * 136 + n] = (f16)acc[i][j][r];
            }
    __syncthreads();
#pragma unroll
    for (int rr = 0; rr < 8; ++rr) {
        int row = wave * 32 + (lane >> 4) * 8 + rr;
        f16x8 vv = *(const f16x8*)(epi + row * 136 + (lane & 15) * 8);
        *(f16x8*)(Wfin + (size_t)b * 262144 + (size_t)(mt * 128 + row) * 512 + nt * 128 + (lane & 15) * 8) = vv;
    }
}

// ---------------- K7: out(b,c,t) f32 = x + bias' + Wfin[b] @ h — k_qk_w-mirror geometry ----------------
// BM=256 o (A=Wfin rows), BN=128 t (B=h rows), BK=64. 4 waves, wave tile 64o x 128t, acc[4][8],
// 64 MFMA/wave per barrier pair. 48KB LDS -> 3 blk/CU.
// Epilogue: 4 wave-passes through [64][132] f32 (0-conflict) -> coalesced stores.
__global__ __launch_bounds__(256, 2) void k_out(const f16* __restrict__ h, const f16* __restrict__ Wfin,
                                                const float* __restrict__ x, const float* __restrict__ bias_p,
                                                float* __restrict__ out) {
    __shared__ __align__(16) char smem[49152];
    int tid = threadIdx.x, lane = tid & 63, wave = tid >> 6;
    int bid = blockIdx.x;
    int lb = (bid & 7) * 256 + (bid >> 3);   // nwg=2048, bijective XCD swizzle
    int batch = lb >> 7;
    int rem = lb & 127;
    int tt = rem >> 1, ot2 = rem & 1;        // ot2 fastest; per batch only 2 distinct A tiles (L2-hot)
    const f16* Abase = Wfin + (size_t)batch * 262144 + (size_t)ot2 * 256 * 512;
    const f16* Bbase = h + ((size_t)batch * 8192 + (size_t)tt * 128) * 512;
    char* As = smem;            // 256 rows x 128 B = 32768
    char* Bs = smem + 32768;    // 128 rows x 128 B = 16384
    const int srow = lane >> 3;
    const int schunk = (lane & 7) ^ srow;
    f32x4 acc[4][8];
#pragma unroll
    for (int i = 0; i < 4; ++i)
#pragma unroll
        for (int j = 0; j < 8; ++j) acc[i][j] = (f32x4){0.f, 0.f, 0.f, 0.f};

    for (int kt = 0; kt < 8; ++kt) {
#pragma unroll
        for (int i = 0; i < 8; ++i) {
            int g = wave * 8 + i;
            gl_lds16(Abase + (size_t)(g * 8 + srow) * 512 + kt * 64 + schunk * 8, As + g * 1024);
        }
#pragma unroll
        for (int i = 0; i < 4; ++i) {
            int g = wave * 4 + i;
            gl_lds16(Bbase + (size_t)(g * 8 + srow) * 512 + kt * 64 + schunk * 8, Bs + g * 1024);
        }
        __syncthreads();
#pragma unroll
        for (int ks = 0; ks < 2; ++ks) {
            f16x8 af[4];
#pragma unroll
            for (int i = 0; i < 4; ++i) {
                int row = wave * 64 + i * 16 + (lane & 15);
                int ch = (ks * 4 + (lane >> 4)) ^ (lane & 7);
                af[i] = *(const f16x8*)(As + row * 128 + ch * 16);
            }
#pragma unroll
            for (int j = 0; j < 8; ++j) {
                int row = j * 16 + (lane & 15);
                int ch = (ks * 4 + (lane >> 4)) ^ (lane & 7);
                f16x8 bf = *(const f16x8*)(Bs + row * 128 + ch * 16);
#pragma unroll
                for (int i = 0; i < 4; ++i)
                    acc[i][j] = __builtin_amdgcn_mfma_f32_16x16x32_f16(af[i], bf, acc[i][j], 0, 0, 0);
            }
        }
        __syncthreads();
    }

    // acc[i][j][r]: o_l = wave*64 + i*16 + (lane>>4)*4 + r (0..255); t_l = j*16 + (lane&15) (0..127)
    float* ep = (float*)smem;                // [64][132] f32 = 33792 B
    const int orow_in = (lane >> 4) * 4;
    for (int ow = 0; ow < 4; ++ow) {
        __syncthreads();                     // prev pass reads / gemm LDS done
        if (wave == ow) {
#pragma unroll
            for (int i = 0; i < 4; ++i)
#pragma unroll
                for (int j = 0; j < 8; ++j)
#pragma unroll
                    for (int r = 0; r < 4; ++r)
                        ep[(i * 16 + orow_in + r) * 132 + j * 16 + (lane & 15)] = acc[i][j][r];
        }
        __syncthreads();
        int o_g0 = ot2 * 256 + ow * 64;
#pragma unroll
        for (int p = 0; p < 8; ++p) {
            int idx = p * 256 + tid;         // 0..2047
            int row = idx >> 5;              // 0..63
            int tq = (idx & 31) * 4;         // 0..124
            int o = o_g0 + row;
            float bpv = bias_p[batch * 512 + o];
            size_t g = ((size_t)batch * 512 + o) * 8192 + (size_t)tt * 128 + tq;
            f32x4 xv = *(const f32x4*)(x + g);
            f32x4 lv = *(const f32x4*)(ep + row * 132 + tq);
            f32x4 ov;
#pragma unroll
            for (int j = 0; j < 4; ++j) ov[j] = xv[j] + bpv + lv[j];
            *(f32x4*)(out + g) = ov;
        }
    }
}

extern "C" void kernel_launch(void* const* d_in, const int* in_sizes, int n_in,
                              void* d_out, int out_size, void* d_ws, size_t ws_size,
                              hipStream_t stream) {
    const float* x   = (const float*)d_in[0];
    const float* gsc = (const float*)d_in[1];
    const float* gbi = (const float*)d_in[2];
    const float* wq  = (const float*)d_in[3];
    const float* bq  = (const float*)d_in[4];  (void)bq;   // zero in setup (see R1 note)
    const float* wk  = (const float*)d_in[5];
    const float* bk  = (const float*)d_in[6];  (void)bk;   // zero in setup (see R1 note)
    const float* wv  = (const float*)d_in[7];
    const float* bv  = (const float*)d_in[8];
    const float* wp  = (const float*)d_in[9];
    const float* bp  = (const float*)d_in[10];
    float* out = (float*)d_out;
    char* ws = (char*)d_ws;

    size_t o_stats = 0;                        // 4 KB
    size_t o_wqkp  = 4096;                     // 1 MB
    size_t o_wvt   = o_wqkp + 1048576;         // 512 KB
    size_t o_biasp = o_wvt + 524288;           // 32 KB
    size_t o_wred  = o_biasp + 32768;          // 1 MB
    size_t o_wpe   = o_wred + 1048576;         // 8 MB
    size_t o_wfin  = o_wpe + 8388608;          // 8 MB
    size_t o_wpart = o_wfin + 8388608;         // 64 MB (64 tt x 16 b x 16 head x 1024)
    size_t o_h     = o_wpart + 67108864;       // 134 MB
    size_t total   = o_h + 134217728;          // ~223 MB
    if (ws_size < total) return;

    float* stats  = (float*)(ws + o_stats);
    f16*   Wqkp   = (f16*)(ws + o_wqkp);
    f16*   WvT    = (f16*)(ws + o_wvt);
    float* bias_p = (float*)(ws + o_biasp);
    float* w_red  = (float*)(ws + o_wred);
    f16*   wpe    = (f16*)(ws + o_wpe);
    f16*   Wfin   = (f16*)(ws + o_wfin);
    float* w_part = (float*)(ws + o_wpart);
    f16*   h      = (f16*)(ws + o_h);

    k_stats_conv<<<3584, 256, 0, stream>>>(x, stats, wq, wk, wv, Wqkp, WvT);
    k_gn_apply  <<<16384, 256, 0, stream>>>(x, stats, gsc, gbi, h);
    k_qk_w      <<<4096,  256, 0, stream>>>(h, Wqkp, w_part);
    k_wreduce   <<<256,   256, 0, stream>>>(w_part, w_red);
    k_wpe       <<<128,   256, 0, stream>>>(w_red, wp, bv, bp, wpe, bias_p);
    k_wfin      <<<256,   256, 0, stream>>>(wpe, WvT, Wfin);
    k_out       <<<2048,  256, 0, stream>>>(h, Wfin, x, bias_p, out);
}

// Round 12
// 517.766 us; speedup vs baseline: 3.4138x; 1.0251x over previous
//
#include <hip/hip_runtime.h>

typedef _Float16 f16;
typedef _Float16 f16x8 __attribute__((ext_vector_type(8)));
typedef float f32x4 __attribute__((ext_vector_type(4)));
typedef float f32x16 __attribute__((ext_vector_type(16)));

// dims: b=16, C=512, t=8192, heads=16 (32 ch each)
// GN folded into weights: xT = f16(x) transpose; scn=gsc*rstd, bi=gbi-mean*scn
//   q/k pre-act = (Wqk . scn) @ xT + (Wqk@bi + bqk)      [k_prep -> k_qk_w]
//   Wfin' = (wpe@WvT) . scn ; out = x + Wfin'@xT + bp + wpe@(bv+u), u = wv@bi

__device__ __forceinline__ void gl_lds16(const f16* g, const void* lds) {
    __builtin_amdgcn_global_load_lds((const __attribute__((address_space(1))) void*)g,
                                     (__attribute__((address_space(3))) void*)lds, 16, 0, 0);
}

// ---------------- K1: transpose x->xT f16 + per-(b,g,tt) partial sums; WvT convert ----------------
__global__ __launch_bounds__(256) void k_tr(const float* __restrict__ x, f16* __restrict__ xT,
                                            float* __restrict__ part,
                                            const float* __restrict__ wv, f16* __restrict__ WvT) {
    int tid = threadIdx.x;
    if (blockIdx.x >= 16384) {
        int idx = (blockIdx.x - 16384) * 256 + tid;   // 0..262143
        int c = idx >> 9, e = idx & 511;
        WvT[idx] = (f16)wv[(size_t)e * 512 + c];
        return;
    }
    __shared__ f16 ldsT[64][72];
    int tt = blockIdx.x & 127, ct = (blockIdx.x >> 7) & 7, b = blockIdx.x >> 10;
    int cc = tid >> 2, tq = tid & 3;
    int c = ct * 64 + cc;
    const float* xp = x + ((size_t)b * 512 + c) * 8192 + tt * 64 + tq * 16;
    float s = 0.f, s2 = 0.f;
#pragma unroll
    for (int q4 = 0; q4 < 4; ++q4) {
        f32x4 v = *(const f32x4*)(xp + q4 * 4);
#pragma unroll
        for (int j = 0; j < 4; ++j) {
            ldsT[tq * 16 + q4 * 4 + j][cc] = (f16)v[j];
            s += v[j]; s2 += v[j] * v[j];
        }
    }
    // group g = tid>>6 covers channels ct*64+g*16..+16 over this block's 64 t: one wave
#pragma unroll
    for (int k = 1; k < 64; k <<= 1) { s += __shfl_xor(s, k); s2 += __shfl_xor(s2, k); }
    if ((tid & 63) == 0) {
        float* pp = part + (((size_t)b * 32 + ct * 4 + (tid >> 6)) * 128 + tt) * 2;
        pp[0] = s; pp[1] = s2;
    }
    __syncthreads();
    int tl = tid >> 2, cq = tid & 3;
    f16x8 v0 = *(const f16x8*)(&ldsT[tl][cq * 16]);
    f16x8 v1 = *(const f16x8*)(&ldsT[tl][cq * 16 + 8]);
    f16* hp = xT + ((size_t)b * 8192 + tt * 64 + tl) * 512 + ct * 64 + cq * 16;
    *(f16x8*)(hp) = v0;
    *(f16x8*)(hp + 8) = v1;
}

// ---------------- K2: finalize stats (mean, rstd) from partials ----------------
__global__ __launch_bounds__(512) void k_stats2(const float* __restrict__ part, float* __restrict__ stats) {
    int i = threadIdx.x;   // b*32+g
    const float* pp = part + (size_t)i * 256;
    float s = 0.f, s2 = 0.f;
    for (int t = 0; t < 128; ++t) { s += pp[t * 2]; s2 += pp[t * 2 + 1]; }
    float mean = s * (1.f / 131072.f);
    float var  = s2 * (1.f / 131072.f) - mean * mean;
    stats[i * 2 + 0] = mean;
    stats[i * 2 + 1] = rsqrtf(var + 1e-6f);
}

// ---------------- K3: per-batch scaled weights + folded biases ----------------
// blocks 0..255:   (b=blk>>4, rg=blk&15): Wqkp2[b] rows rg*64..+64 (= Wqk_perm . scn), qkb
// blocks 256..383: (b=(blk-256)>>3, ug&7): u[b][e] = wv[e]@bi[b]
__global__ __launch_bounds__(256) void k_prep(const float* __restrict__ wq, const float* __restrict__ wk,
                                              const float* __restrict__ wv,
                                              const float* __restrict__ gsc, const float* __restrict__ gbi,
                                              const float* __restrict__ stats,
                                              const float* __restrict__ bq, const float* __restrict__ bk,
                                              f16* __restrict__ Wqkp2, float* __restrict__ qkb,
                                              float* __restrict__ u) {
    __shared__ float scn[512], bi[512], red[256];
    int tid = threadIdx.x;
    int blk = blockIdx.x;
    int b = (blk < 256) ? (blk >> 4) : ((blk - 256) >> 3);
    for (int i = tid; i < 512; i += 256) {
        float mean = stats[(b * 32 + (i >> 4)) * 2 + 0];
        float rstd = stats[(b * 32 + (i >> 4)) * 2 + 1];
        float sc = gsc[i] * rstd;
        scn[i] = sc;
        bi[i] = gbi[i] - mean * sc;
    }
    __syncthreads();
    if (blk < 256) {
        int rg = blk & 15;
        int pr = rg * 64 + (tid >> 2);      // perm row 0..1023
        int cq = tid & 3;
        int hg = pr >> 8, ri = pr & 255;
        int hl = ri >> 6, qk = (ri >> 5) & 1, ch = ri & 31;
        int src = (hg * 4 + hl) * 32 + ch;
        const float* wrow = (qk ? wk : wq) + (size_t)src * 512;
        f16* orow = Wqkp2 + ((size_t)b * 1024 + pr) * 512;
        float dot = 0.f;
        for (int c0 = cq * 128; c0 < cq * 128 + 128; c0 += 8) {
            f16x8 o8;
#pragma unroll
            for (int j = 0; j < 8; ++j) {
                float wv_ = wrow[c0 + j] * scn[c0 + j];
                o8[j] = (f16)wv_;
                dot += wv_ * bi[c0 + j];
            }
            *(f16x8*)(orow + c0) = o8;
        }
        red[tid] = dot;
        __syncthreads();
        if (cq == 0)
            qkb[(size_t)b * 1024 + pr] = red[tid] + red[tid + 1] + red[tid + 2] + red[tid + 3]
                                         + (qk ? bk[src] : bq[src]);
    } else {
        int ug = (blk - 256) & 7;
        int e = ug * 64 + (tid >> 2);
        int cq = tid & 3;
        const float* wrow = wv + (size_t)e * 512;
        float dot = 0.f;
        for (int c = cq * 128; c < cq * 128 + 128; ++c) dot += wrow[c] * bi[c];
        red[tid] = dot;
        __syncthreads();
        if (cq == 0) u[(size_t)b * 512 + e] = red[tid] + red[tid + 1] + red[tid + 2] + red[tid + 3];
    }
}

// ---------------- shared GEMM core (BM=BN=128, BK=64, K=512) — used by k_wfin ----------------
__device__ __forceinline__ void gemm_core(const f16* __restrict__ Abase, int lda,
                                          const f16* __restrict__ Bbase,
                                          char* smem, int tid, f32x4 acc[4][4]) {
    const int lane = tid & 63, wave = tid >> 6;
    const int wm = wave >> 1, wn = wave & 1;
    char* As = smem;
    char* Bs = smem + 16384;
    const int srow = (lane >> 3);
    const int schunk = (lane & 7) ^ srow;
    for (int kt = 0; kt < 8; ++kt) {
#pragma unroll
        for (int i = 0; i < 4; ++i) {
            int row = (wave * 4 + i) * 8 + srow;
            gl_lds16(Abase + (size_t)row * lda + kt * 64 + schunk * 8, As + (wave * 4 + i) * 1024);
            gl_lds16(Bbase + (size_t)row * 512 + kt * 64 + schunk * 8, Bs + (wave * 4 + i) * 1024);
        }
        __syncthreads();
#pragma unroll
        for (int ks = 0; ks < 2; ++ks) {
            f16x8 af[4], bf[4];
#pragma unroll
            for (int i = 0; i < 4; ++i) {
                int row = wm * 64 + i * 16 + (lane & 15);
                int ch = (ks * 4 + (lane >> 4)) ^ (lane & 7);
                af[i] = *(const f16x8*)(As + row * 128 + ch * 16);
            }
#pragma unroll
            for (int j = 0; j < 4; ++j) {
                int row = wn * 64 + j * 16 + (lane & 15);
                int ch = (ks * 4 + (lane >> 4)) ^ (lane & 7);
                bf[j] = *(const f16x8*)(Bs + row * 128 + ch * 16);
            }
#pragma unroll
            for (int i = 0; i < 4; ++i)
#pragma unroll
                for (int j = 0; j < 4; ++j)
                    acc[i][j] = __builtin_amdgcn_mfma_f32_16x16x32_f16(af[i], bf[j], acc[i][j], 0, 0, 0);
        }
        __syncthreads();
    }
}

// ---------------- K4: fused qk GEMM + bias + softmax + w partials ----------------
// BM=256 (4 heads x {q32|k32}), BN=128 t, K=512. A = per-batch scaled Wqkp2. 48KB LDS -> 3 blk/CU.
__global__ __launch_bounds__(256, 2) void k_qk_w(const f16* __restrict__ xT, const f16* __restrict__ Wqkp2,
                                                 const float* __restrict__ qkb, float* __restrict__ w_part) {
    __shared__ __align__(16) char smem[49152];
    int tid = threadIdx.x, lane = tid & 63, wave = tid >> 6;
    int bid = blockIdx.x;
    int lb = (bid & 7) * 512 + (bid >> 3);   // nwg=4096, bijective XCD swizzle
    int batch = lb >> 8;
    int rem = lb & 255;
    int tt = rem >> 2, hg = rem & 3;         // hg fastest: 4 blocks share one xT tile
    const f16* Abase = Wqkp2 + ((size_t)batch * 1024 + hg * 256) * 512;
    const f16* Bbase = xT + ((size_t)batch * 8192 + (size_t)tt * 128) * 512;
    char* As = smem;            // 256 rows x 128 B
    char* Bs = smem + 32768;    // 128 rows x 128 B
    const int srow = lane >> 3;
    const int schunk = (lane & 7) ^ srow;
    f32x4 acc[4][8];
#pragma unroll
    for (int i = 0; i < 4; ++i)
#pragma unroll
        for (int j = 0; j < 8; ++j) acc[i][j] = (f32x4){0.f, 0.f, 0.f, 0.f};

    for (int kt = 0; kt < 8; ++kt) {
#pragma unroll
        for (int i = 0; i < 8; ++i) {
            int g = wave * 8 + i;
            gl_lds16(Abase + (size_t)(g * 8 + srow) * 512 + kt * 64 + schunk * 8, As + g * 1024);
        }
#pragma unroll
        for (int i = 0; i < 4; ++i) {
            int g = wave * 4 + i;
            gl_lds16(Bbase + (size_t)(g * 8 + srow) * 512 + kt * 64 + schunk * 8, Bs + g * 1024);
        }
        __syncthreads();
#pragma unroll
        for (int ks = 0; ks < 2; ++ks) {
            f16x8 af[4];
#pragma unroll
            for (int i = 0; i < 4; ++i) {
                int row = wave * 64 + i * 16 + (lane & 15);
                int ch = (ks * 4 + (lane >> 4)) ^ (lane & 7);
                af[i] = *(const f16x8*)(As + row * 128 + ch * 16);
            }
#pragma unroll
            for (int j = 0; j < 8; ++j) {
                int row = j * 16 + (lane & 15);
                int ch = (ks * 4 + (lane >> 4)) ^ (lane & 7);
                f16x8 bf = *(const f16x8*)(Bs + row * 128 + ch * 16);
#pragma unroll
                for (int i = 0; i < 4; ++i)
                    acc[i][j] = __builtin_amdgcn_mfma_f32_16x16x32_f16(af[i], bf, acc[i][j], 0, 0, 0);
            }
        }
        __syncthreads();
    }

    // ---- epilogue: add folded bias, softmax over 32 ch, w += q_sm @ k_sm^T ----
    // acc row (A-row) = wave*64 + i*16 + (lane>>4)*4 + r ; i = qk*2+i2 -> ch = i2*16+(lane>>4)*4+r
    float qb[2][8];
#pragma unroll
    for (int qk = 0; qk < 2; ++qk)
#pragma unroll
        for (int i2 = 0; i2 < 2; ++i2)
#pragma unroll
            for (int r = 0; r < 4; ++r)
                qb[qk][i2 * 4 + r] = qkb[(size_t)batch * 1024 + hg * 256 + wave * 64 + qk * 32 +
                                         i2 * 16 + (lane >> 4) * 4 + r];
    f16* qbuf = (f16*)(smem + wave * 9216);
    f16* kbuf = qbuf + 32 * 72;
    f32x16 wacc;
#pragma unroll
    for (int i = 0; i < 16; ++i) wacc[i] = 0.f;

#pragma unroll
    for (int th = 0; th < 2; ++th) {
#pragma unroll
        for (int jl = 0; jl < 4; ++jl) {
            int j = th * 4 + jl;
#pragma unroll
            for (int qk = 0; qk < 2; ++qk) {
                int ib = qk * 2;
                float v0[8];
#pragma unroll
                for (int i2 = 0; i2 < 2; ++i2)
#pragma unroll
                    for (int r = 0; r < 4; ++r)
                        v0[i2 * 4 + r] = acc[ib + i2][j][r] + qb[qk][i2 * 4 + r];
                float mx = v0[0];
#pragma unroll
                for (int i = 1; i < 8; ++i) mx = fmaxf(mx, v0[i]);
                mx = fmaxf(mx, __shfl_xor(mx, 16));
                mx = fmaxf(mx, __shfl_xor(mx, 32));
                float s = 0.f;
#pragma unroll
                for (int i = 0; i < 8; ++i) { v0[i] = __expf(v0[i] - mx); s += v0[i]; }
                s += __shfl_xor(s, 16);
                s += __shfl_xor(s, 32);
                float inv = 1.f / s;
                f16* dst = qk ? kbuf : qbuf;
                int tcol = jl * 16 + (lane & 15);
#pragma unroll
                for (int i2 = 0; i2 < 2; ++i2)
#pragma unroll
                    for (int r = 0; r < 4; ++r) {
                        int c = i2 * 16 + (lane >> 4) * 4 + r;
                        dst[c * 72 + tcol] = (f16)(v0[i2 * 4 + r] * inv);
                    }
            }
        }
#pragma unroll
        for (int ks = 0; ks < 4; ++ks) {
            f16x8 a  = *(const f16x8*)(qbuf + (lane & 31) * 72 + ks * 16 + (lane >> 5) * 8);
            f16x8 bb = *(const f16x8*)(kbuf + (lane & 31) * 72 + ks * 16 + (lane >> 5) * 8);
            wacc = __builtin_amdgcn_mfma_f32_32x32x16_f16(a, bb, wacc, 0, 0, 0);
        }
    }
    int ghead = hg * 4 + wave;
    float* wpo = w_part + (((size_t)tt * 16 + batch) * 16 + ghead) * 1024;
#pragma unroll
    for (int r = 0; r < 16; ++r) {
        int row = (r & 3) + 8 * (r >> 2) + 4 * (lane >> 5);
        wpo[row * 32 + (lane & 31)] = wacc[r];
    }
}

// ---------------- K5: reduce w partials over 64 t-tiles ----------------
__global__ __launch_bounds__(256) void k_wreduce(const float* __restrict__ w_part, float* __restrict__ w_red) {
    int blk = blockIdx.x;   // b*16+head
    int tid = threadIdx.x;
    f32x4 s = (f32x4){0.f, 0.f, 0.f, 0.f};
    for (int tt = 0; tt < 64; ++tt) {
        f32x4 v = *(const f32x4*)(w_part + ((size_t)tt * 256 + blk) * 1024 + tid * 4);
        s += v;
    }
    *(f32x4*)(w_red + (size_t)blk * 1024 + tid * 4) = s;
}

// ---------------- K6: wpe[b][o][e]; bias_p = bp + wpe@(bv+u) ----------------
__global__ __launch_bounds__(256) void k_wpe(const float* __restrict__ w_red, const float* __restrict__ wp,
                                             const float* __restrict__ bv, const float* __restrict__ u,
                                             const float* __restrict__ bp,
                                             f16* __restrict__ wpe, float* __restrict__ bias_p) {
    __shared__ float wl[16384];
    __shared__ float bred[256];
    int tid = threadIdx.x;
    int b = blockIdx.x >> 3, ot = blockIdx.x & 7;
    for (int idx = tid; idx < 16384; idx += 256) wl[idx] = w_red[(size_t)b * 16384 + idx];
    __syncthreads();
    int o = ot * 64 + (tid >> 2);
    int cq = tid & 3;
    float bacc = 0.f;
#pragma unroll
    for (int ng = 0; ng < 4; ++ng) {
        int n = cq * 4 + ng;
        float a[32];
#pragma unroll
        for (int d = 0; d < 32; ++d) a[d] = 0.f;
        for (int e = 0; e < 32; ++e) {
            float wv = wp[(size_t)o * 512 + n * 32 + e];
#pragma unroll
            for (int d = 0; d < 32; ++d) a[d] += wv * wl[n * 1024 + e * 32 + d];
        }
#pragma unroll
        for (int dc = 0; dc < 4; ++dc) {
            f16x8 o8;
#pragma unroll
            for (int j = 0; j < 8; ++j) o8[j] = (f16)a[dc * 8 + j];
            *(f16x8*)(wpe + ((size_t)b * 512 + o) * 512 + n * 32 + dc * 8) = o8;
        }
#pragma unroll
        for (int d = 0; d < 32; ++d) bacc += a[d] * (bv[n * 32 + d] + u[(size_t)b * 512 + n * 32 + d]);
    }
    bred[tid] = bacc;
    __syncthreads();
    if ((tid & 3) == 0)
        bias_p[(size_t)b * 512 + o] = bp[o] + bred[tid] + bred[tid + 1] + bred[tid + 2] + bred[tid + 3];
}

// ---------------- K7: Wfin'[b] = (wpe[b] @ WvT) . scn[b]  (f16) ----------------
__global__ __launch_bounds__(256) void k_wfin(const f16* __restrict__ wpe, const f16* __restrict__ WvT,
                                              const float* __restrict__ gsc, const float* __restrict__ stats,
                                              f16* __restrict__ Wfin) {
    __shared__ __align__(16) char smem[34816];
    int tid = threadIdx.x, lane = tid & 63, wave = tid >> 6;
    int wm = wave >> 1, wn = wave & 1;
    int bid = blockIdx.x;
    int b = bid >> 4, mt = (bid >> 2) & 3, nt = bid & 3;
    const f16* Abase = wpe + (size_t)b * 262144 + (size_t)mt * 128 * 512;
    const f16* Bbase = WvT + (size_t)nt * 128 * 512;
    f32x4 acc[4][4];
#pragma unroll
    for (int i = 0; i < 4; ++i)
#pragma unroll
        for (int j = 0; j < 4; ++j) acc[i][j] = (f32x4){0.f, 0.f, 0.f, 0.f};
    gemm_core(Abase, 512, Bbase, smem, tid, acc);
    float scnj[4];
#pragma unroll
    for (int j = 0; j < 4; ++j) {
        int col = nt * 128 + wn * 64 + j * 16 + (lane & 15);
        scnj[j] = gsc[col] * stats[(b * 32 + (col >> 4)) * 2 + 1];
    }
    f16* epi = (f16*)smem;
#pragma unroll
    for (int i = 0; i < 4; ++i)
#pragma unroll
        for (int j = 0; j < 4; ++j)
#pragma unroll
            for (int r = 0; r < 4; ++r) {
                int m = wm * 64 + i * 16 + (lane >> 4) * 4 + r;
                int n = wn * 64 + j * 16 + (lane & 15);
                epi[m * 136 + n] = (f16)(acc[i][j][r] * scnj[j]);
            }
    __syncthreads();
#pragma unroll
    for (int rr = 0; rr < 8; ++rr) {
        int row = wave * 32 + (lane >> 4) * 8 + rr;
        f16x8 vv = *(const f16x8*)(epi + row * 136 + (lane & 15) * 8);
        *(f16x8*)(Wfin + (size_t)b * 262144 + (size_t)(mt * 128 + row) * 512 + nt * 128 + (lane & 15) * 8) = vv;
    }
}

// ---------------- K8: out(b,c,t) f32 = x + bias' + Wfin'[b] @ xT ----------------
__global__ __launch_bounds__(256, 2) void k_out(const f16* __restrict__ xT, const f16* __restrict__ Wfin,
                                                const float* __restrict__ x, const float* __restrict__ bias_p,
                                                float* __restrict__ out) {
    __shared__ __align__(16) char smem[49152];
    int tid = threadIdx.x, lane = tid & 63, wave = tid >> 6;
    int bid = blockIdx.x;
    int lb = (bid & 7) * 256 + (bid >> 3);   // nwg=2048, bijective XCD swizzle
    int batch = lb >> 7;
    int rem = lb & 127;
    int tt = rem >> 1, ot2 = rem & 1;
    const f16* Abase = Wfin + (size_t)batch * 262144 + (size_t)ot2 * 256 * 512;
    const f16* Bbase = xT + ((size_t)batch * 8192 + (size_t)tt * 128) * 512;
    char* As = smem;
    char* Bs = smem + 32768;
    const int srow = lane >> 3;
    const int schunk = (lane & 7) ^ srow;
    f32x4 acc[4][8];
#pragma unroll
    for (int i = 0; i < 4; ++i)
#pragma unroll
        for (int j = 0; j < 8; ++j) acc[i][j] = (f32x4){0.f, 0.f, 0.f, 0.f};

    for (int kt = 0; kt < 8; ++kt) {
#pragma unroll
        for (int i = 0; i < 8; ++i) {
            int g = wave * 8 + i;
            gl_lds16(Abase + (size_t)(g * 8 + srow) * 512 + kt * 64 + schunk * 8, As + g * 1024);
        }
#pragma unroll
        for (int i = 0; i < 4; ++i) {
            int g = wave * 4 + i;
            gl_lds16(Bbase + (size_t)(g * 8 + srow) * 512 + kt * 64 + schunk * 8, Bs + g * 1024);
        }
        __syncthreads();
#pragma unroll
        for (int ks = 0; ks < 2; ++ks) {
            f16x8 af[4];
#pragma unroll
            for (int i = 0; i < 4; ++i) {
                int row = wave * 64 + i * 16 + (lane & 15);
                int ch = (ks * 4 + (lane >> 4)) ^ (lane & 7);
                af[i] = *(const f16x8*)(As + row * 128 + ch * 16);
            }
#pragma unroll
            for (int j = 0; j < 8; ++j) {
                int row = j * 16 + (lane & 15);
                int ch = (ks * 4 + (lane >> 4)) ^ (lane & 7);
                f16x8 bf = *(const f16x8*)(Bs + row * 128 + ch * 16);
#pragma unroll
                for (int i = 0; i < 4; ++i)
                    acc[i][j] = __builtin_amdgcn_mfma_f32_16x16x32_f16(af[i], bf, acc[i][j], 0, 0, 0);
            }
        }
        __syncthreads();
    }

    float* ep = (float*)smem;                // [64][132] f32
    const int orow_in = (lane >> 4) * 4;
    for (int ow = 0; ow < 4; ++ow) {
        __syncthreads();
        if (wave == ow) {
#pragma unroll
            for (int i = 0; i < 4; ++i)
#pragma unroll
                for (int j = 0; j < 8; ++j)
#pragma unroll
                    for (int r = 0; r < 4; ++r)
                        ep[(i * 16 + orow_in + r) * 132 + j * 16 + (lane & 15)] = acc[i][j][r];
        }
        __syncthreads();
        int o_g0 = ot2 * 256 + ow * 64;
#pragma unroll
        for (int p = 0; p < 8; ++p) {
            int idx = p * 256 + tid;
            int row = idx >> 5;
            int tq = (idx & 31) * 4;
            int o = o_g0 + row;
            float bpv = bias_p[batch * 512 + o];
            size_t g = ((size_t)batch * 512 + o) * 8192 + (size_t)tt * 128 + tq;
            f32x4 xv = *(const f32x4*)(x + g);
            f32x4 lv = *(const f32x4*)(ep + row * 132 + tq);
            f32x4 ov;
#pragma unroll
            for (int j = 0; j < 4; ++j) ov[j] = xv[j] + bpv + lv[j];
            *(f32x4*)(out + g) = ov;
        }
    }
}

extern "C" void kernel_launch(void* const* d_in, const int* in_sizes, int n_in,
                              void* d_out, int out_size, void* d_ws, size_t ws_size,
                              hipStream_t stream) {
    const float* x   = (const float*)d_in[0];
    const float* gsc = (const float*)d_in[1];
    const float* gbi = (const float*)d_in[2];
    const float* wq  = (const float*)d_in[3];
    const float* bq  = (const float*)d_in[4];
    const float* wk  = (const float*)d_in[5];
    const float* bk  = (const float*)d_in[6];
    const float* wv  = (const float*)d_in[7];
    const float* bv  = (const float*)d_in[8];
    const float* wp  = (const float*)d_in[9];
    const float* bp  = (const float*)d_in[10];
    float* out = (float*)d_out;
    char* ws = (char*)d_ws;

    size_t o_stats = 0;                        // 4 KB
    size_t o_part  = 4096;                     // 512 KB
    size_t o_qkb   = o_part + 524288;          // 64 KB
    size_t o_u     = o_qkb + 65536;            // 32 KB
    size_t o_biasp = o_u + 32768;              // 32 KB
    size_t o_wvt   = o_biasp + 32768;          // 512 KB
    size_t o_wred  = o_wvt + 524288;           // 1 MB
    size_t o_wpe   = o_wred + 1048576;         // 8 MB
    size_t o_wfin  = o_wpe + 8388608;          // 8 MB
    size_t o_wqkp2 = o_wfin + 8388608;         // 16 MB
    size_t o_wpart = o_wqkp2 + 16777216;       // 64 MB
    size_t o_xT    = o_wpart + 67108864;       // 134 MB
    size_t total   = o_xT + 134217728;         // ~238 MB
    if (ws_size < total) return;

    float* stats  = (float*)(ws + o_stats);
    float* part   = (float*)(ws + o_part);
    float* qkb    = (float*)(ws + o_qkb);
    float* u      = (float*)(ws + o_u);
    float* bias_p = (float*)(ws + o_biasp);
    f16*   WvT    = (f16*)(ws + o_wvt);
    float* w_red  = (float*)(ws + o_wred);
    f16*   wpe    = (f16*)(ws + o_wpe);
    f16*   Wfin   = (f16*)(ws + o_wfin);
    f16*   Wqkp2  = (f16*)(ws + o_wqkp2);
    float* w_part = (float*)(ws + o_wpart);
    f16*   xT     = (f16*)(ws + o_xT);

    k_tr     <<<17408, 256, 0, stream>>>(x, xT, part, wv, WvT);
    k_stats2 <<<1,     512, 0, stream>>>(part, stats);
    k_prep   <<<384,   256, 0, stream>>>(wq, wk, wv, gsc, gbi, stats, bq, bk, Wqkp2, qkb, u);
    k_qk_w   <<<4096,  256, 0, stream>>>(xT, Wqkp2, qkb, w_part);
    k_wreduce<<<256,   256, 0, stream>>>(w_part, w_red);
    k_wpe    <<<128,   256, 0, stream>>>(w_red, wp, bv, u, bp, wpe, bias_p);
    k_wfin   <<<256,   256, 0, stream>>>(wpe, WvT, gsc, stats, Wfin);
    k_out    <<<2048,  256, 0, stream>>>(xT, Wfin, x, bias_p, out);
}

// Round 13
// 493.721 us; speedup vs baseline: 3.5801x; 1.0487x over previous
//
#include <hip/hip_runtime.h>

typedef _Float16 f16;
typedef _Float16 f16x8 __attribute__((ext_vector_type(8)));
typedef _Float16 f16x4 __attribute__((ext_vector_type(4)));
typedef float f32x4 __attribute__((ext_vector_type(4)));
typedef float f32x16 __attribute__((ext_vector_type(16)));

// dims: b=16, C=512, t=8192, heads=16 (32 ch each)
// GN folded into weights: xT = f16(x) transpose; scn=gsc*rstd, bi=gbi-mean*scn
//   q/k pre-act = (Wqk . scn) @ xT + (Wqk@bi + bqk)      [k_prep -> k_qk_w]
//   Wfin' = (wpe@WvT) . scn ; out = x + Wfin'@xT + bp + wpe@(bv+u), u = wv@bi

__device__ __forceinline__ void gl_lds16(const f16* g, const void* lds) {
    __builtin_amdgcn_global_load_lds((const __attribute__((address_space(1))) void*)g,
                                     (__attribute__((address_space(3))) void*)lds, 16, 0, 0);
}

// ---------------- K1: transpose x->xT f16 + per-(b,g,tt) partial sums; WvT convert ----------------
__global__ __launch_bounds__(256) void k_tr(const float* __restrict__ x, f16* __restrict__ xT,
                                            float* __restrict__ part,
                                            const float* __restrict__ wv, f16* __restrict__ WvT) {
    int tid = threadIdx.x;
    if (blockIdx.x >= 16384) {
        int idx = (blockIdx.x - 16384) * 256 + tid;   // 0..262143
        int c = idx >> 9, e = idx & 511;
        WvT[idx] = (f16)wv[(size_t)e * 512 + c];
        return;
    }
    __shared__ f16 ldsT[64][72];
    int tt = blockIdx.x & 127, ct = (blockIdx.x >> 7) & 7, b = blockIdx.x >> 10;
    int cc = tid >> 2, tq = tid & 3;
    int c = ct * 64 + cc;
    const float* xp = x + ((size_t)b * 512 + c) * 8192 + tt * 64 + tq * 16;
    float s = 0.f, s2 = 0.f;
#pragma unroll
    for (int q4 = 0; q4 < 4; ++q4) {
        f32x4 v = *(const f32x4*)(xp + q4 * 4);
#pragma unroll
        for (int j = 0; j < 4; ++j) {
            ldsT[tq * 16 + q4 * 4 + j][cc] = (f16)v[j];
            s += v[j]; s2 += v[j] * v[j];
        }
    }
#pragma unroll
    for (int k = 1; k < 64; k <<= 1) { s += __shfl_xor(s, k); s2 += __shfl_xor(s2, k); }
    if ((tid & 63) == 0) {
        float* pp = part + (((size_t)b * 32 + ct * 4 + (tid >> 6)) * 128 + tt) * 2;
        pp[0] = s; pp[1] = s2;
    }
    __syncthreads();
    int tl = tid >> 2, cq = tid & 3;
    f16x8 v0 = *(const f16x8*)(&ldsT[tl][cq * 16]);
    f16x8 v1 = *(const f16x8*)(&ldsT[tl][cq * 16 + 8]);
    f16* hp = xT + ((size_t)b * 8192 + tt * 64 + tl) * 512 + ct * 64 + cq * 16;
    *(f16x8*)(hp) = v0;
    *(f16x8*)(hp + 8) = v1;
}

// ---------------- K2: per-batch scaled weights + folded biases (stats derived in-block) ----------------
// blocks 0..255:   (b=blk>>4, rg=blk&15): Wqkp2[b] rows rg*64..+64 (= Wqk_perm . scn), qkb
// blocks 256..383: (b=(blk-256)>>3, ug=&7): u[b][e] = wv[e]@bi[b]; ug==0 publishes stats[b] for k_wfin
__global__ __launch_bounds__(256) void k_prep(const float* __restrict__ wq, const float* __restrict__ wk,
                                              const float* __restrict__ wv,
                                              const float* __restrict__ gsc, const float* __restrict__ gbi,
                                              const float* __restrict__ part,
                                              const float* __restrict__ bq, const float* __restrict__ bk,
                                              f16* __restrict__ Wqkp2, float* __restrict__ qkb,
                                              float* __restrict__ u, float* __restrict__ stats) {
    __shared__ float scn[512], bi[512], red[256];
    int tid = threadIdx.x;
    int blk = blockIdx.x;
    int b = (blk < 256) ? (blk >> 4) : ((blk - 256) >> 3);
    // ---- in-block stats from partials (scn/bi as scratch) ----
    {
        int g = tid >> 3, ch = tid & 7;
        const float* pp = part + (((size_t)b * 32 + g) * 128 + ch * 16) * 2;
        float s = 0.f, s2 = 0.f;
        for (int t2 = 0; t2 < 16; ++t2) { s += pp[t2 * 2]; s2 += pp[t2 * 2 + 1]; }
        scn[tid] = s; bi[tid] = s2;
    }
    __syncthreads();
    if (tid < 32) {
        float S = 0.f, S2 = 0.f;
#pragma unroll
        for (int j = 0; j < 8; ++j) { S += scn[tid * 8 + j]; S2 += bi[tid * 8 + j]; }
        float mean = S * (1.f / 131072.f);
        float var  = S2 * (1.f / 131072.f) - mean * mean;
        float rstd = rsqrtf(var + 1e-6f);
        red[tid] = mean;
        red[128 + tid] = rstd;
        if (blk >= 256 && ((blk - 256) & 7) == 0) {
            stats[(b * 32 + tid) * 2 + 0] = mean;
            stats[(b * 32 + tid) * 2 + 1] = rstd;
        }
    }
    __syncthreads();
    for (int i = tid; i < 512; i += 256) {
        float sc = gsc[i] * red[128 + (i >> 4)];
        scn[i] = sc;
        bi[i] = gbi[i] - red[i >> 4] * sc;
    }
    __syncthreads();
    if (blk < 256) {
        int rg = blk & 15;
        int pr = rg * 64 + (tid >> 2);      // perm row 0..1023
        int cq = tid & 3;
        int hg = pr >> 8, ri = pr & 255;
        int hl = ri >> 6, qk = (ri >> 5) & 1, ch = ri & 31;
        int src = (hg * 4 + hl) * 32 + ch;
        const float* wrow = (qk ? wk : wq) + (size_t)src * 512;
        f16* orow = Wqkp2 + ((size_t)b * 1024 + pr) * 512;
        float dot = 0.f;
        for (int c0 = cq * 128; c0 < cq * 128 + 128; c0 += 8) {
            f16x8 o8;
#pragma unroll
            for (int j = 0; j < 8; ++j) {
                float wv_ = wrow[c0 + j] * scn[c0 + j];
                o8[j] = (f16)wv_;
                dot += wv_ * bi[c0 + j];
            }
            *(f16x8*)(orow + c0) = o8;
        }
        red[tid] = dot;
        __syncthreads();
        if (cq == 0)
            qkb[(size_t)b * 1024 + pr] = red[tid] + red[tid + 1] + red[tid + 2] + red[tid + 3]
                                         + (qk ? bk[src] : bq[src]);
    } else {
        int ug = (blk - 256) & 7;
        int e = ug * 64 + (tid >> 2);
        int cq = tid & 3;
        const float* wrow = wv + (size_t)e * 512;
        float dot = 0.f;
        for (int c = cq * 128; c < cq * 128 + 128; ++c) dot += wrow[c] * bi[c];
        red[tid] = dot;
        __syncthreads();
        if (cq == 0) u[(size_t)b * 512 + e] = red[tid] + red[tid + 1] + red[tid + 2] + red[tid + 3];
    }
}

// ---------------- shared GEMM core (BM=BN=128, BK=64, K=512) — used by k_wfin ----------------
__device__ __forceinline__ void gemm_core(const f16* __restrict__ Abase, int lda,
                                          const f16* __restrict__ Bbase,
                                          char* smem, int tid, f32x4 acc[4][4]) {
    const int lane = tid & 63, wave = tid >> 6;
    const int wm = wave >> 1, wn = wave & 1;
    char* As = smem;
    char* Bs = smem + 16384;
    const int srow = (lane >> 3);
    const int schunk = (lane & 7) ^ srow;
    for (int kt = 0; kt < 8; ++kt) {
#pragma unroll
        for (int i = 0; i < 4; ++i) {
            int row = (wave * 4 + i) * 8 + srow;
            gl_lds16(Abase + (size_t)row * lda + kt * 64 + schunk * 8, As + (wave * 4 + i) * 1024);
            gl_lds16(Bbase + (size_t)row * 512 + kt * 64 + schunk * 8, Bs + (wave * 4 + i) * 1024);
        }
        __syncthreads();
#pragma unroll
        for (int ks = 0; ks < 2; ++ks) {
            f16x8 af[4], bf[4];
#pragma unroll
            for (int i = 0; i < 4; ++i) {
                int row = wm * 64 + i * 16 + (lane & 15);
                int ch = (ks * 4 + (lane >> 4)) ^ (lane & 7);
                af[i] = *(const f16x8*)(As + row * 128 + ch * 16);
            }
#pragma unroll
            for (int j = 0; j < 4; ++j) {
                int row = wn * 64 + j * 16 + (lane & 15);
                int ch = (ks * 4 + (lane >> 4)) ^ (lane & 7);
                bf[j] = *(const f16x8*)(Bs + row * 128 + ch * 16);
            }
#pragma unroll
            for (int i = 0; i < 4; ++i)
#pragma unroll
                for (int j = 0; j < 4; ++j)
                    acc[i][j] = __builtin_amdgcn_mfma_f32_16x16x32_f16(af[i], bf[j], acc[i][j], 0, 0, 0);
        }
        __syncthreads();
    }
}

// ---------------- K3: fused qk GEMM + bias + softmax + w partials ----------------
// BM=256 (4 heads x {q32|k32}), BN=128 t, K=512. A = per-batch scaled Wqkp2. 48KB LDS -> 3 blk/CU.
__global__ __launch_bounds__(256, 2) void k_qk_w(const f16* __restrict__ xT, const f16* __restrict__ Wqkp2,
                                                 const float* __restrict__ qkb, f16* __restrict__ w_part) {
    __shared__ __align__(16) char smem[49152];
    int tid = threadIdx.x, lane = tid & 63, wave = tid >> 6;
    int bid = blockIdx.x;
    int lb = (bid & 7) * 512 + (bid >> 3);   // nwg=4096, bijective XCD swizzle
    int batch = lb >> 8;
    int rem = lb & 255;
    int tt = rem >> 2, hg = rem & 3;         // hg fastest: 4 blocks share one xT tile
    const f16* Abase = Wqkp2 + ((size_t)batch * 1024 + hg * 256) * 512;
    const f16* Bbase = xT + ((size_t)batch * 8192 + (size_t)tt * 128) * 512;
    char* As = smem;            // 256 rows x 128 B
    char* Bs = smem + 32768;    // 128 rows x 128 B
    const int srow = lane >> 3;
    const int schunk = (lane & 7) ^ srow;
    f32x4 acc[4][8];
#pragma unroll
    for (int i = 0; i < 4; ++i)
#pragma unroll
        for (int j = 0; j < 8; ++j) acc[i][j] = (f32x4){0.f, 0.f, 0.f, 0.f};

    for (int kt = 0; kt < 8; ++kt) {
#pragma unroll
        for (int i = 0; i < 8; ++i) {
            int g = wave * 8 + i;
            gl_lds16(Abase + (size_t)(g * 8 + srow) * 512 + kt * 64 + schunk * 8, As + g * 1024);
        }
#pragma unroll
        for (int i = 0; i < 4; ++i) {
            int g = wave * 4 + i;
            gl_lds16(Bbase + (size_t)(g * 8 + srow) * 512 + kt * 64 + schunk * 8, Bs + g * 1024);
        }
        __syncthreads();
#pragma unroll
        for (int ks = 0; ks < 2; ++ks) {
            f16x8 af[4];
#pragma unroll
            for (int i = 0; i < 4; ++i) {
                int row = wave * 64 + i * 16 + (lane & 15);
                int ch = (ks * 4 + (lane >> 4)) ^ (lane & 7);
                af[i] = *(const f16x8*)(As + row * 128 + ch * 16);
            }
#pragma unroll
            for (int j = 0; j < 8; ++j) {
                int row = j * 16 + (lane & 15);
                int ch = (ks * 4 + (lane >> 4)) ^ (lane & 7);
                f16x8 bf = *(const f16x8*)(Bs + row * 128 + ch * 16);
#pragma unroll
                for (int i = 0; i < 4; ++i)
                    acc[i][j] = __builtin_amdgcn_mfma_f32_16x16x32_f16(af[i], bf, acc[i][j], 0, 0, 0);
            }
        }
        __syncthreads();
    }

    // ---- epilogue: add folded bias, softmax over 32 ch, w += q_sm @ k_sm^T ----
    float qb[2][8];
#pragma unroll
    for (int qk = 0; qk < 2; ++qk)
#pragma unroll
        for (int i2 = 0; i2 < 2; ++i2)
#pragma unroll
            for (int r = 0; r < 4; ++r)
                qb[qk][i2 * 4 + r] = qkb[(size_t)batch * 1024 + hg * 256 + wave * 64 + qk * 32 +
                                         i2 * 16 + (lane >> 4) * 4 + r];
    f16* qbuf = (f16*)(smem + wave * 9216);
    f16* kbuf = qbuf + 32 * 72;
    f32x16 wacc;
#pragma unroll
    for (int i = 0; i < 16; ++i) wacc[i] = 0.f;

#pragma unroll
    for (int th = 0; th < 2; ++th) {
#pragma unroll
        for (int jl = 0; jl < 4; ++jl) {
            int j = th * 4 + jl;
#pragma unroll
            for (int qk = 0; qk < 2; ++qk) {
                int ib = qk * 2;
                float v0[8];
#pragma unroll
                for (int i2 = 0; i2 < 2; ++i2)
#pragma unroll
                    for (int r = 0; r < 4; ++r)
                        v0[i2 * 4 + r] = acc[ib + i2][j][r] + qb[qk][i2 * 4 + r];
                float mx = v0[0];
#pragma unroll
                for (int i = 1; i < 8; ++i) mx = fmaxf(mx, v0[i]);
                mx = fmaxf(mx, __shfl_xor(mx, 16));
                mx = fmaxf(mx, __shfl_xor(mx, 32));
                float s = 0.f;
#pragma unroll
                for (int i = 0; i < 8; ++i) { v0[i] = __expf(v0[i] - mx); s += v0[i]; }
                s += __shfl_xor(s, 16);
                s += __shfl_xor(s, 32);
                float inv = 1.f / s;
                f16* dst = qk ? kbuf : qbuf;
                int tcol = jl * 16 + (lane & 15);
#pragma unroll
                for (int i2 = 0; i2 < 2; ++i2)
#pragma unroll
                    for (int r = 0; r < 4; ++r) {
                        int c = i2 * 16 + (lane >> 4) * 4 + r;
                        dst[c * 72 + tcol] = (f16)(v0[i2 * 4 + r] * inv);
                    }
            }
        }
#pragma unroll
        for (int ks = 0; ks < 4; ++ks) {
            f16x8 a  = *(const f16x8*)(qbuf + (lane & 31) * 72 + ks * 16 + (lane >> 5) * 8);
            f16x8 bb = *(const f16x8*)(kbuf + (lane & 31) * 72 + ks * 16 + (lane >> 5) * 8);
            wacc = __builtin_amdgcn_mfma_f32_32x32x16_f16(a, bb, wacc, 0, 0, 0);
        }
    }
    int ghead = hg * 4 + wave;
    f16* wpo = w_part + (((size_t)tt * 16 + batch) * 16 + ghead) * 1024;
#pragma unroll
    for (int r = 0; r < 16; ++r) {
        int row = (r & 3) + 8 * (r >> 2) + 4 * (lane >> 5);
        wpo[row * 32 + (lane & 31)] = (f16)wacc[r];
    }
}

// ---------------- K4: reduce w partials (f16) over 64 t-tiles -> f32 ----------------
__global__ __launch_bounds__(256) void k_wreduce(const f16* __restrict__ w_part, float* __restrict__ w_red) {
    int blk = blockIdx.x;   // b*16+head
    int tid = threadIdx.x;
    f32x4 s = (f32x4){0.f, 0.f, 0.f, 0.f};
    for (int tt = 0; tt < 64; ++tt) {
        f16x4 v = *(const f16x4*)(w_part + ((size_t)tt * 256 + blk) * 1024 + tid * 4);
#pragma unroll
        for (int j = 0; j < 4; ++j) s[j] += (float)v[j];
    }
    *(f32x4*)(w_red + (size_t)blk * 1024 + tid * 4) = s;
}

// ---------------- K5: wpe[b][o][e]; bias_p = bp + wpe@(bv+u) ----------------
__global__ __launch_bounds__(256) void k_wpe(const float* __restrict__ w_red, const float* __restrict__ wp,
                                             const float* __restrict__ bv, const float* __restrict__ u,
                                             const float* __restrict__ bp,
                                             f16* __restrict__ wpe, float* __restrict__ bias_p) {
    __shared__ float wl[16384];
    __shared__ float bred[256];
    int tid = threadIdx.x;
    int b = blockIdx.x >> 3, ot = blockIdx.x & 7;
    for (int idx = tid; idx < 16384; idx += 256) wl[idx] = w_red[(size_t)b * 16384 + idx];
    __syncthreads();
    int o = ot * 64 + (tid >> 2);
    int cq = tid & 3;
    float bacc = 0.f;
#pragma unroll
    for (int ng = 0; ng < 4; ++ng) {
        int n = cq * 4 + ng;
        float a[32];
#pragma unroll
        for (int d = 0; d < 32; ++d) a[d] = 0.f;
        for (int e = 0; e < 32; ++e) {
            float wv = wp[(size_t)o * 512 + n * 32 + e];
#pragma unroll
            for (int d = 0; d < 32; ++d) a[d] += wv * wl[n * 1024 + e * 32 + d];
        }
#pragma unroll
        for (int dc = 0; dc < 4; ++dc) {
            f16x8 o8;
#pragma unroll
            for (int j = 0; j < 8; ++j) o8[j] = (f16)a[dc * 8 + j];
            *(f16x8*)(wpe + ((size_t)b * 512 + o) * 512 + n * 32 + dc * 8) = o8;
        }
#pragma unroll
        for (int d = 0; d < 32; ++d) bacc += a[d] * (bv[n * 32 + d] + u[(size_t)b * 512 + n * 32 + d]);
    }
    bred[tid] = bacc;
    __syncthreads();
    if ((tid & 3) == 0)
        bias_p[(size_t)b * 512 + o] = bp[o] + bred[tid] + bred[tid + 1] + bred[tid + 2] + bred[tid + 3];
}

// ---------------- K6: Wfin'[b] = (wpe[b] @ WvT) . scn[b]  (f16) ----------------
__global__ __launch_bounds__(256) void k_wfin(const f16* __restrict__ wpe, const f16* __restrict__ WvT,
                                              const float* __restrict__ gsc, const float* __restrict__ stats,
                                              f16* __restrict__ Wfin) {
    __shared__ __align__(16) char smem[34816];
    int tid = threadIdx.x, lane = tid & 63, wave = tid >> 6;
    int wm = wave >> 1, wn = wave & 1;
    int bid = blockIdx.x;
    int b = bid >> 4, mt = (bid >> 2) & 3, nt = bid & 3;
    const f16* Abase = wpe + (size_t)b * 262144 + (size_t)mt * 128 * 512;
    const f16* Bbase = WvT + (size_t)nt * 128 * 512;
    f32x4 acc[4][4];
#pragma unroll
    for (int i = 0; i < 4; ++i)
#pragma unroll
        for (int j = 0; j < 4; ++j) acc[i][j] = (f32x4){0.f, 0.f, 0.f, 0.f};
    gemm_core(Abase, 512, Bbase, smem, tid, acc);
    float scnj[4];
#pragma unroll
    for (int j = 0; j < 4; ++j) {
        int col = nt * 128 + wn * 64 + j * 16 + (lane & 15);
        scnj[j] = gsc[col] * stats[(b * 32 + (col >> 4)) * 2 + 1];
    }
    f16* epi = (f16*)smem;
#pragma unroll
    for (int i = 0; i < 4; ++i)
#pragma unroll
        for (int j = 0; j < 4; ++j)
#pragma unroll
            for (int r = 0; r < 4; ++r) {
                int m = wm * 64 + i * 16 + (lane >> 4) * 4 + r;
                int n = wn * 64 + j * 16 + (lane & 15);
                epi[m * 136 + n] = (f16)(acc[i][j][r] * scnj[j]);
            }
    __syncthreads();
#pragma unroll
    for (int rr = 0; rr < 8; ++rr) {
        int row = wave * 32 + (lane >> 4) * 8 + rr;
        f16x8 vv = *(const f16x8*)(epi + row * 136 + (lane & 15) * 8);
        *(f16x8*)(Wfin + (size_t)b * 262144 + (size_t)(mt * 128 + row) * 512 + nt * 128 + (lane & 15) * 8) = vv;
    }
}

// ---------------- K7: out(b,c,t) f32 = x + bias' + Wfin'[b] @ xT ----------------
// f16 epilogue buffer [128][132] (33.8 KB), 2 passes x 2 waves writing -> coalesced f32x4 stores.
__global__ __launch_bounds__(256, 2) void k_out(const f16* __restrict__ xT, const f16* __restrict__ Wfin,
                                                const float* __restrict__ x, const float* __restrict__ bias_p,
                                                float* __restrict__ out) {
    __shared__ __align__(16) char smem[49152];
    int tid = threadIdx.x, lane = tid & 63, wave = tid >> 6;
    int bid = blockIdx.x;
    int lb = (bid & 7) * 256 + (bid >> 3);   // nwg=2048, bijective XCD swizzle
    int batch = lb >> 7;
    int rem = lb & 127;
    int tt = rem >> 1, ot2 = rem & 1;
    const f16* Abase = Wfin + (size_t)batch * 262144 + (size_t)ot2 * 256 * 512;
    const f16* Bbase = xT + ((size_t)batch * 8192 + (size_t)tt * 128) * 512;
    char* As = smem;
    char* Bs = smem + 32768;
    const int srow = lane >> 3;
    const int schunk = (lane & 7) ^ srow;
    f32x4 acc[4][8];
#pragma unroll
    for (int i = 0; i < 4; ++i)
#pragma unroll
        for (int j = 0; j < 8; ++j) acc[i][j] = (f32x4){0.f, 0.f, 0.f, 0.f};

    for (int kt = 0; kt < 8; ++kt) {
#pragma unroll
        for (int i = 0; i < 8; ++i) {
            int g = wave * 8 + i;
            gl_lds16(Abase + (size_t)(g * 8 + srow) * 512 + kt * 64 + schunk * 8, As + g * 1024);
        }
#pragma unroll
        for (int i = 0; i < 4; ++i) {
            int g = wave * 4 + i;
            gl_lds16(Bbase + (size_t)(g * 8 + srow) * 512 + kt * 64 + schunk * 8, Bs + g * 1024);
        }
        __syncthreads();
#pragma unroll
        for (int ks = 0; ks < 2; ++ks) {
            f16x8 af[4];
#pragma unroll
            for (int i = 0; i < 4; ++i) {
                int row = wave * 64 + i * 16 + (lane & 15);
                int ch = (ks * 4 + (lane >> 4)) ^ (lane & 7);
                af[i] = *(const f16x8*)(As + row * 128 + ch * 16);
            }
#pragma unroll
            for (int j = 0; j < 8; ++j) {
                int row = j * 16 + (lane & 15);
                int ch = (ks * 4 + (lane >> 4)) ^ (lane & 7);
                f16x8 bf = *(const f16x8*)(Bs + row * 128 + ch * 16);
#pragma unroll
                for (int i = 0; i < 4; ++i)
                    acc[i][j] = __builtin_amdgcn_mfma_f32_16x16x32_f16(af[i], bf, acc[i][j], 0, 0, 0);
            }
        }
        __syncthreads();
    }

    // acc[i][j][r]: o_l = wave*64 + i*16 + (lane>>4)*4 + r (0..255); t_l = j*16 + (lane&15) (0..127)
    f16* ep = (f16*)smem;                    // [128][132] f16 = 33792 B
    const int orow_in = (lane >> 4) * 4;
    for (int pp = 0; pp < 2; ++pp) {
        __syncthreads();                     // prev pass reads / gemm LDS done
        if ((wave >> 1) == pp) {
            f16* myep = ep + (size_t)(wave & 1) * 64 * 132;
#pragma unroll
            for (int i = 0; i < 4; ++i)
#pragma unroll
                for (int j = 0; j < 8; ++j)
#pragma unroll
                    for (int r = 0; r < 4; ++r)
                        myep[(i * 16 + orow_in + r) * 132 + j * 16 + (lane & 15)] = (f16)acc[i][j][r];
        }
        __syncthreads();
        int o_g0 = ot2 * 256 + pp * 128;
#pragma unroll
        for (int p = 0; p < 16; ++p) {
            int idx = p * 256 + tid;         // 0..4095
            int row = idx >> 5;              // 0..127
            int tq = (idx & 31) * 4;         // 0..124
            int o = o_g0 + row;
            float bpv = bias_p[batch * 512 + o];
            size_t g = ((size_t)batch * 512 + o) * 8192 + (size_t)tt * 128 + tq;
            f32x4 xv = *(const f32x4*)(x + g);
            f16x4 lv = *(const f16x4*)(ep + row * 132 + tq);
            f32x4 ov;
#pragma unroll
            for (int j = 0; j < 4; ++j) ov[j] = xv[j] + bpv + (float)lv[j];
            *(f32x4*)(out + g) = ov;
        }
    }
}

extern "C" void kernel_launch(void* const* d_in, const int* in_sizes, int n_in,
                              void* d_out, int out_size, void* d_ws, size_t ws_size,
                              hipStream_t stream) {
    const float* x   = (const float*)d_in[0];
    const float* gsc = (const float*)d_in[1];
    const float* gbi = (const float*)d_in[2];
    const float* wq  = (const float*)d_in[3];
    const float* bq  = (const float*)d_in[4];
    const float* wk  = (const float*)d_in[5];
    const float* bk  = (const float*)d_in[6];
    const float* wv  = (const float*)d_in[7];
    const float* bv  = (const float*)d_in[8];
    const float* wp  = (const float*)d_in[9];
    const float* bp  = (const float*)d_in[10];
    float* out = (float*)d_out;
    char* ws = (char*)d_ws;

    size_t o_stats = 0;                        // 4 KB
    size_t o_part  = 4096;                     // 512 KB
    size_t o_qkb   = o_part + 524288;          // 64 KB
    size_t o_u     = o_qkb + 65536;            // 32 KB
    size_t o_biasp = o_u + 32768;              // 32 KB
    size_t o_wvt   = o_biasp + 32768;          // 512 KB
    size_t o_wred  = o_wvt + 524288;           // 1 MB
    size_t o_wpe   = o_wred + 1048576;         // 8 MB
    size_t o_wfin  = o_wpe + 8388608;          // 8 MB
    size_t o_wqkp2 = o_wfin + 8388608;         // 16 MB
    size_t o_wpart = o_wqkp2 + 16777216;       // 32 MB (f16 now)
    size_t o_xT    = o_wpart + 33554432;       // 134 MB
    size_t total   = o_xT + 134217728;         // ~207 MB
    if (ws_size < total) return;

    float* stats  = (float*)(ws + o_stats);
    float* part   = (float*)(ws + o_part);
    float* qkb    = (float*)(ws + o_qkb);
    float* u      = (float*)(ws + o_u);
    float* bias_p = (float*)(ws + o_biasp);
    f16*   WvT    = (f16*)(ws + o_wvt);
    float* w_red  = (float*)(ws + o_wred);
    f16*   wpe    = (f16*)(ws + o_wpe);
    f16*   Wfin   = (f16*)(ws + o_wfin);
    f16*   Wqkp2  = (f16*)(ws + o_wqkp2);
    f16*   w_part = (f16*)(ws + o_wpart);
    f16*   xT     = (f16*)(ws + o_xT);

    k_tr     <<<17408, 256, 0, stream>>>(x, xT, part, wv, WvT);
    k_prep   <<<384,   256, 0, stream>>>(wq, wk, wv, gsc, gbi, part, bq, bk, Wqkp2, qkb, u, stats);
    k_qk_w   <<<4096,  256, 0, stream>>>(xT, Wqkp2, qkb, w_part);
    k_wreduce<<<256,   256, 0, stream>>>(w_part, w_red);
    k_wpe    <<<128,   256, 0, stream>>>(w_red, wp, bv, u, bp, wpe, bias_p);
    k_wfin   <<<256,   256, 0, stream>>>(wpe, WvT, gsc, stats, Wfin);
    k_out    <<<2048,  256, 0, stream>>>(xT, Wfin, x, bias_p, out);
}